// Round 9
// baseline (763.032 us; speedup 1.0000x reference)
//
#include <hip/hip_runtime.h>
#include <hip/hip_bf16.h>
#include <math.h>

#define NN 200000
#define NE 6400000

#define BSHIFT 8
#define BNODES 256                     // nodes per bucket
#define NB 782                         // ceil(NN / BNODES)
#define CAP 8704                       // bucket capacity (mean 8192, realized max ~8513)
#define NBLK_SC 1024
#define CHUNK (NE / NBLK_SC)           // 6250

typedef unsigned uvec4 __attribute__((ext_vector_type(4)));
typedef float   fvec2 __attribute__((ext_vector_type(2)));

// ---- workspace layout (4-byte words) ----
#define W_DACC 0                       // double (2 words)
#define W_UV   4                       // 8 floats
#define W_CUR  16                      // NB uints
#define W_META 1024                    // NB*CAP u32: src(18b) | dl(8b)<<18
#define W_PAY  (W_META + NB*CAP)       // NB*CAP float2 {hs.x, hs.y}  (8B-aligned: even)
#define W_ACC  (W_PAY + 2*NB*CAP)      // 6*NN f32 planar [j*NN+n]; layer2 reuses 3 planes
#define W_Z2   (W_ACC + 6*NN)          // 2*NN f32 (float2/node)
#define W_TOTAL (W_Z2 + 2*NN)          // ~22.0M words = 88.1 MB

// Native LDS float atomic add (fire-and-forget ds_add_f32).
__device__ __forceinline__ void ds_faddf(float* p, float v) {
    asm volatile("ds_add_f32 %0, %1" : : "v"((unsigned)(uintptr_t)p), "v"(v));
}

__global__ void k_init(unsigned* __restrict__ ws) {
    int t = blockIdx.x * blockDim.x + threadIdx.x;
    if (t == 0) *(double*)ws = 0.0;
    if (t < NB) ws[W_CUR + t] = 0u;
}

// u_i(h) = sum_o fc1[h][i][o]*attn1[h][o];  v_i(h) = sum_o fc1[h][i][o]*attn1[h][16+o]
__global__ void k_prep(const float* __restrict__ fc1, const float* __restrict__ attn1,
                       float* __restrict__ uv) {
    int t = threadIdx.x;
    if (t < 8) {
        int h = t >> 2, r = t & 3, i = r & 1, isv = r >> 1;
        double s = 0.0;
        for (int o = 0; o < 16; ++o)
            s += (double)fc1[h * 32 + i * 16 + o] * (double)attn1[h * 32 + isv * 16 + o];
        uv[t] = (float)s;
    }
}

// radix partition by dst bucket; gathers h[src] once and embeds it in the record.
__global__ void k_scatter(const int* __restrict__ src, const int* __restrict__ dst,
                          const float2* __restrict__ h,
                          fvec2* __restrict__ pay, unsigned* __restrict__ meta,
                          unsigned* __restrict__ cur) {
    __shared__ unsigned cnt[NB], gbase[NB], rk[NB];
    for (int i = threadIdx.x; i < NB; i += blockDim.x) { cnt[i] = 0u; rk[i] = 0u; }
    __syncthreads();
    int beg = blockIdx.x * CHUNK, end = beg + CHUNK;
    for (int i = beg + threadIdx.x; i < end; i += blockDim.x)
        atomicAdd(&cnt[(unsigned)__builtin_nontemporal_load(dst + i) >> BSHIFT], 1u);
    __syncthreads();
    for (int i = threadIdx.x; i < NB; i += blockDim.x)
        gbase[i] = atomicAdd(&cur[i], cnt[i]);
    __syncthreads();
    for (int i = beg + threadIdx.x; i < end; i += blockDim.x) {
        int d = __builtin_nontemporal_load(dst + i);
        int b = d >> BSHIFT;
        unsigned rank = atomicAdd(&rk[b], 1u);
        unsigned slot = gbase[b] + rank;
        if (slot < CAP) {
            int sn = __builtin_nontemporal_load(src + i);
            float2 hs = h[sn];                          // the one random gather per edge
            size_t o = (size_t)b * CAP + slot;
            fvec2 p; p.x = hs.x; p.y = hs.y;
            pay[o]  = p;                                // normal stores: L2 write-merge
            meta[o] = (unsigned)sn | ((unsigned)(d & (BNODES - 1)) << 18);
        }
    }
}

// layer-1 edge pass: PURE STREAM (payload in record) + LDS accumulation.
// One block per bucket; planar acc {den0,A0,B0,den1,A1,B1}[node], written once (S=1).
__launch_bounds__(512)
__global__ void k_gat1(const fvec2* __restrict__ pay, const unsigned* __restrict__ meta,
                       const unsigned* __restrict__ cur, const float2* __restrict__ h,
                       const float* __restrict__ uv, float* __restrict__ accc) {
    __shared__ float acc[6 * BNODES];                 // 6 KB, plane j at j*BNODES
    __shared__ float2 c01[BNODES];                    // per-dst hd-terms
    int b = blockIdx.x;
    int nodebase = b << BSHIFT;
    int nn = min(BNODES, NN - nodebase);
    float u00 = uv[0], u10 = uv[1], v00 = uv[2], v10 = uv[3];
    float u01 = uv[4], u11 = uv[5], v01 = uv[6], v11 = uv[7];
    for (int i = threadIdx.x; i < 6 * BNODES; i += 512) acc[i] = 0.f;
    for (int i = threadIdx.x; i < nn; i += 512) {
        float2 hd = h[nodebase + i];
        c01[i] = make_float2(fmaf(hd.x, v00, hd.y * v10), fmaf(hd.x, v01, hd.y * v11));
    }
    __syncthreads();
    int cnt = min((int)cur[b], CAP);
    const fvec2*    pp = pay  + (size_t)b * CAP;
    const unsigned* pm = meta + (size_t)b * CAP;
#pragma unroll 4
    for (int i = threadIdx.x; i < cnt; i += 512) {
        unsigned m = __builtin_nontemporal_load(pm + i);
        fvec2 hs   = __builtin_nontemporal_load(pp + i);
        int dl = m >> 18;
        float2 c = c01[dl];
        float e0 = fmaf(hs.x, u00, fmaf(hs.y, u10, c.x));
        float e1 = fmaf(hs.x, u01, fmaf(hs.y, u11, c.y));
        e0 = e0 >= 0.f ? e0 : 0.01f * e0;
        e1 = e1 >= 0.f ? e1 : 0.01f * e1;
        float ex0 = __expf(e0);
        float ex1 = __expf(e1);
        ds_faddf(&acc[0 * BNODES + dl], ex0);
        ds_faddf(&acc[1 * BNODES + dl], ex0 * hs.x);
        ds_faddf(&acc[2 * BNODES + dl], ex0 * hs.y);
        ds_faddf(&acc[3 * BNODES + dl], ex1);
        ds_faddf(&acc[4 * BNODES + dl], ex1 * hs.x);
        ds_faddf(&acc[5 * BNODES + dl], ex1 * hs.y);
    }
    asm volatile("s_waitcnt lgkmcnt(0)" ::: "memory");
    __syncthreads();
    for (int w = threadIdx.x; w < 6 * BNODES; w += 512) {
        int j = w >> BSHIFT, k = w & (BNODES - 1);
        if (k < nn) accc[(size_t)j * NN + nodebase + k] = acc[w];
    }
}

// finalize layer1 (softmax div + elu), z2 = x @ fc2 (single copy now)
__global__ void k_node1(const float* __restrict__ accc, const float* __restrict__ fc1,
                        const float* __restrict__ fc2, float2* __restrict__ z2) {
    int n = blockIdx.x * blockDim.x + threadIdx.x;
    if (n >= NN) return;
    float a[6];
#pragma unroll
    for (int j = 0; j < 6; ++j) a[j] = accc[(size_t)j * NN + n];
    float den0 = a[0], A0 = a[1], B0 = a[2];
    float den1 = a[3], A1 = a[4], B1 = a[5];
    float x[32];
#pragma unroll
    for (int o = 0; o < 16; ++o) {
        float t0 = den0 > 0.f ? (A0 * fc1[o]      + B0 * fc1[16 + o]) / den0 : 0.f;
        float t1 = den1 > 0.f ? (A1 * fc1[32 + o] + B1 * fc1[48 + o]) / den1 : 0.f;
        x[o]      = t0 > 0.f ? t0 : expm1f(t0);
        x[16 + o] = t1 > 0.f ? t1 : expm1f(t1);
    }
    float z0 = 0.f, z1 = 0.f;
#pragma unroll
    for (int j = 0; j < 32; ++j) {
        z0 += x[j] * fc2[2 * j];
        z1 += x[j] * fc2[2 * j + 1];
    }
    z2[n] = make_float2(z0, z1);                      // normal store: z2 L2-hot for gat2
}

// layer-2 edge pass: stream meta, gather z2[sn]; LDS {den,num0,num1}; exp shift 48
__launch_bounds__(512)
__global__ void k_gat2(const unsigned* __restrict__ meta, const unsigned* __restrict__ cur,
                       const float2* __restrict__ z2, const float* __restrict__ attn2,
                       float* __restrict__ acc2c) {
    __shared__ float acc[3 * BNODES];
    __shared__ float cd[BNODES];
    int b = blockIdx.x;
    int nodebase = b << BSHIFT;
    int nn = min(BNODES, NN - nodebase);
    float a0 = attn2[0], a1 = attn2[1], a2 = attn2[2], a3 = attn2[3];
    for (int i = threadIdx.x; i < 3 * BNODES; i += 512) acc[i] = 0.f;
    for (int i = threadIdx.x; i < nn; i += 512) {
        float2 zd = z2[nodebase + i];
        cd[i] = fmaf(zd.x, a2, zd.y * a3);
    }
    __syncthreads();
    int cnt = min((int)cur[b], CAP);
    const unsigned* pm = meta + (size_t)b * CAP;
#pragma unroll 4
    for (int i = threadIdx.x; i < cnt; i += 512) {
        unsigned m = __builtin_nontemporal_load(pm + i);
        int sn = m & 0x3FFFF, dl = m >> 18;
        float2 zs = z2[sn];                            // the remaining random gather
        float e = fmaf(zs.x, a0, fmaf(zs.y, a1, cd[dl]));
        e = e >= 0.f ? e : 0.01f * e;
        float ex = __expf(e - 48.f);   // cancels in softmax; e<=~88, den>=deg*e^-49
        ds_faddf(&acc[0 * BNODES + dl], ex);
        ds_faddf(&acc[1 * BNODES + dl], ex * zs.x);
        ds_faddf(&acc[2 * BNODES + dl], ex * zs.y);
    }
    asm volatile("s_waitcnt lgkmcnt(0)" ::: "memory");
    __syncthreads();
    for (int w = threadIdx.x; w < 3 * BNODES; w += 512) {
        int j = w >> BSHIFT, k = w & (BNODES - 1);
        if (k < nn) acc2c[(size_t)j * NN + nodebase + k] = acc[w];
    }
}

// x2 = num/den; f64 dot with mlp_w; block reduce; f64 atomic
__global__ void k_final(const float* __restrict__ acc2c, const float* __restrict__ mlp_w,
                        double* __restrict__ dacc) {
    int n = blockIdx.x * blockDim.x + threadIdx.x;
    double v = 0.0;
    if (n < NN) {
        float den = acc2c[(size_t)0 * NN + n];
        float n0  = acc2c[(size_t)1 * NN + n];
        float n1  = acc2c[(size_t)2 * NN + n];
        float x0 = den > 0.f ? n0 / den : 0.f;
        float x1 = den > 0.f ? n1 / den : 0.f;
        v = (double)x0 * (double)__builtin_nontemporal_load(&mlp_w[2 * n]) +
            (double)x1 * (double)__builtin_nontemporal_load(&mlp_w[2 * n + 1]);
    }
    for (int off = 32; off > 0; off >>= 1) v += __shfl_down(v, off);
    __shared__ double sm[4];
    int lane = threadIdx.x & 63, wid = threadIdx.x >> 6;
    if (lane == 0) sm[wid] = v;
    __syncthreads();
    if (threadIdx.x == 0) {
        double sum = sm[0] + sm[1] + sm[2] + sm[3];
        unsafeAtomicAdd(dacc, sum);
    }
}

__global__ void k_out(const double* __restrict__ dacc, const float* __restrict__ mlp_b,
                      float* __restrict__ out) {
    double logit = dacc[0] + (double)mlp_b[0];
    out[0] = (float)(1.0 / (1.0 + exp(-logit)));
}

extern "C" void kernel_launch(void* const* d_in, const int* in_sizes, int n_in,
                              void* d_out, int out_size, void* d_ws, size_t ws_size,
                              hipStream_t stream) {
    const float* h     = (const float*)d_in[0];
    const int*   src   = (const int*)d_in[1];
    const int*   dst   = (const int*)d_in[2];
    const float* fc1   = (const float*)d_in[3];
    const float* attn1 = (const float*)d_in[4];
    const float* fc2   = (const float*)d_in[5];
    const float* attn2 = (const float*)d_in[6];
    const float* mlp_w = (const float*)d_in[7];
    const float* mlp_b = (const float*)d_in[8];
    float* out = (float*)d_out;

    unsigned* ws   = (unsigned*)d_ws;
    double*   dacc = (double*)d_ws;
    float*    uv   = (float*)(ws + W_UV);
    unsigned* cur  = ws + W_CUR;
    unsigned* meta = ws + W_META;
    fvec2*    pay  = (fvec2*)(ws + W_PAY);
    float*    accc = (float*)(ws + W_ACC);   // 6 planes layer1; first 3 reused layer2
    float2*   z2   = (float2*)(ws + W_Z2);

    hipLaunchKernelGGL(k_init, dim3(4), dim3(256), 0, stream, ws);
    hipLaunchKernelGGL(k_prep, dim3(1), dim3(64), 0, stream, fc1, attn1, uv);
    hipLaunchKernelGGL(k_scatter, dim3(NBLK_SC), dim3(256), 0, stream,
                       src, dst, (const float2*)h, pay, meta, cur);
    hipLaunchKernelGGL(k_gat1, dim3(NB), dim3(512), 0, stream,
                       pay, meta, cur, (const float2*)h, uv, accc);
    hipLaunchKernelGGL(k_node1, dim3((NN + 255) / 256), dim3(256), 0, stream,
                       accc, fc1, fc2, z2);
    hipLaunchKernelGGL(k_gat2, dim3(NB), dim3(512), 0, stream,
                       meta, cur, (const float2*)z2, attn2, accc);
    hipLaunchKernelGGL(k_final, dim3((NN + 255) / 256), dim3(256), 0, stream,
                       accc, mlp_w, dacc);
    hipLaunchKernelGGL(k_out, dim3(1), dim3(1), 0, stream, dacc, mlp_b, out);
}

// Round 10
// 608.448 us; speedup vs baseline: 1.2541x; 1.2541x over previous
//
#include <hip/hip_runtime.h>
#include <hip/hip_bf16.h>
#include <math.h>

#define NN 200000
#define NE 6400000

#define BSHIFT 8
#define BNODES 256                     // nodes per bucket
#define NB 782                         // ceil(NN / BNODES)
#define CAP 8704                       // bucket capacity (mean 8184); mult of 4
#define PL 257                         // padded LDS plane stride (bank rotation)
#define NBLK_SC 1024
#define CHUNK (NE / NBLK_SC)           // 6250

typedef unsigned uvec4 __attribute__((ext_vector_type(4)));

// ---- workspace layout (4-byte words) ----
#define W_DACC 0                       // double (2 words)
#define W_UV   4                       // 8 floats
#define W_CUR  16                      // NB uints
#define W_REC  1024                    // NB*CAP uvec4 records {sn|dl<<18, hs.x, hs.y, 0}
#define W_ACC  (W_REC + 4*NB*CAP)      // 6*NN f32 planar [j*NN+n]; layer2 reuses 3 planes
#define W_Z2   (W_ACC + 6*NN)          // 2*NN f32 (float2/node)
#define W_TOTAL (W_Z2 + 2*NN)          // ~28.8M words = 115.3 MB

// Native LDS float atomic add (fire-and-forget ds_add_f32).
__device__ __forceinline__ void ds_faddf(float* p, float v) {
    asm volatile("ds_add_f32 %0, %1" : : "v"((unsigned)(uintptr_t)p), "v"(v));
}

__global__ void k_init(unsigned* __restrict__ ws) {
    int t = blockIdx.x * blockDim.x + threadIdx.x;
    if (t == 0) *(double*)ws = 0.0;
    if (t < NB) ws[W_CUR + t] = 0u;
}

// u_i(h) = sum_o fc1[h][i][o]*attn1[h][o];  v_i(h) = sum_o fc1[h][i][o]*attn1[h][16+o]
__global__ void k_prep(const float* __restrict__ fc1, const float* __restrict__ attn1,
                       float* __restrict__ uv) {
    int t = threadIdx.x;
    if (t < 8) {
        int h = t >> 2, r = t & 3, i = r & 1, isv = r >> 1;
        double s = 0.0;
        for (int o = 0; o < 16; ++o)
            s += (double)fc1[h * 32 + i * 16 + o] * (double)attn1[h * 32 + isv * 16 + o];
        uv[t] = (float)s;
    }
}

// radix partition by dst bucket; embeds h[src] in a single 16B record per edge.
__global__ void k_scatter(const int* __restrict__ src, const int* __restrict__ dst,
                          const float2* __restrict__ h,
                          uvec4* __restrict__ rec, unsigned* __restrict__ cur) {
    __shared__ unsigned cnt[NB], gbase[NB], rk[NB];
    for (int i = threadIdx.x; i < NB; i += blockDim.x) { cnt[i] = 0u; rk[i] = 0u; }
    __syncthreads();
    int beg = blockIdx.x * CHUNK, end = beg + CHUNK;
    for (int i = beg + threadIdx.x; i < end; i += blockDim.x)
        atomicAdd(&cnt[(unsigned)dst[i] >> BSHIFT], 1u);      // normal load: primes L2
    __syncthreads();
    for (int i = threadIdx.x; i < NB; i += blockDim.x)
        gbase[i] = atomicAdd(&cur[i], cnt[i]);
    __syncthreads();
    for (int i = beg + threadIdx.x; i < end; i += blockDim.x) {
        int d = dst[i];                                       // L2 hit (primed above)
        int b = d >> BSHIFT;
        unsigned rank = atomicAdd(&rk[b], 1u);
        unsigned slot = gbase[b] + rank;
        if (slot < CAP) {
            int sn = __builtin_nontemporal_load(src + i);
            float2 hs = h[sn];                                // one random gather per edge
            uvec4 r;
            r[0] = (unsigned)sn | ((unsigned)(d & (BNODES - 1)) << 18);
            r[1] = __float_as_uint(hs.x);
            r[2] = __float_as_uint(hs.y);
            r[3] = 0u;
            rec[(size_t)b * CAP + slot] = r;                  // single 16B store
        }
    }
}

// layer-1 edge pass: PURE STREAM + LDS accumulation, bank-rotated planes.
__launch_bounds__(512)
__global__ void k_gat1(const uvec4* __restrict__ rec, const unsigned* __restrict__ cur,
                       const float2* __restrict__ h, const float* __restrict__ uv,
                       float* __restrict__ accc) {
    __shared__ float acc[6 * PL];                     // plane j at j*PL, bank (dl+j)%32
    __shared__ float2 c01[BNODES];                    // per-dst hd-terms
    int b = blockIdx.x;
    int nodebase = b << BSHIFT;
    int nn = min(BNODES, NN - nodebase);
    float u00 = uv[0], u10 = uv[1], v00 = uv[2], v10 = uv[3];
    float u01 = uv[4], u11 = uv[5], v01 = uv[6], v11 = uv[7];
    for (int i = threadIdx.x; i < 6 * PL; i += 512) acc[i] = 0.f;
    for (int i = threadIdx.x; i < nn; i += 512) {
        float2 hd = h[nodebase + i];
        c01[i] = make_float2(fmaf(hd.x, v00, hd.y * v10), fmaf(hd.x, v01, hd.y * v11));
    }
    __syncthreads();
    int cnt = min((int)cur[b], CAP);
    const uvec4* pr = rec + (size_t)b * CAP;
#pragma unroll 4
    for (int i = threadIdx.x; i < cnt; i += 512) {
        uvec4 r = __builtin_nontemporal_load(pr + i);
        int dl = r[0] >> 18;
        float hx = __uint_as_float(r[1]);
        float hy = __uint_as_float(r[2]);
        float2 c = c01[dl];
        float e0 = fmaf(hx, u00, fmaf(hy, u10, c.x));
        float e1 = fmaf(hx, u01, fmaf(hy, u11, c.y));
        e0 = e0 >= 0.f ? e0 : 0.01f * e0;
        e1 = e1 >= 0.f ? e1 : 0.01f * e1;
        float ex0 = __expf(e0);
        float ex1 = __expf(e1);
        ds_faddf(&acc[0 * PL + dl], ex0);
        ds_faddf(&acc[1 * PL + dl], ex0 * hx);
        ds_faddf(&acc[2 * PL + dl], ex0 * hy);
        ds_faddf(&acc[3 * PL + dl], ex1);
        ds_faddf(&acc[4 * PL + dl], ex1 * hx);
        ds_faddf(&acc[5 * PL + dl], ex1 * hy);
    }
    asm volatile("s_waitcnt lgkmcnt(0)" ::: "memory");
    __syncthreads();
    for (int w = threadIdx.x; w < 6 * BNODES; w += 512) {
        int j = w >> BSHIFT, k = w & (BNODES - 1);
        if (k < nn) accc[(size_t)j * NN + nodebase + k] = acc[j * PL + k];
    }
}

// finalize layer1 (softmax div + elu), z2 = x @ fc2
__global__ void k_node1(const float* __restrict__ accc, const float* __restrict__ fc1,
                        const float* __restrict__ fc2, float2* __restrict__ z2) {
    int n = blockIdx.x * blockDim.x + threadIdx.x;
    if (n >= NN) return;
    float a[6];
#pragma unroll
    for (int j = 0; j < 6; ++j) a[j] = accc[(size_t)j * NN + n];
    float den0 = a[0], A0 = a[1], B0 = a[2];
    float den1 = a[3], A1 = a[4], B1 = a[5];
    float x[32];
#pragma unroll
    for (int o = 0; o < 16; ++o) {
        float t0 = den0 > 0.f ? (A0 * fc1[o]      + B0 * fc1[16 + o]) / den0 : 0.f;
        float t1 = den1 > 0.f ? (A1 * fc1[32 + o] + B1 * fc1[48 + o]) / den1 : 0.f;
        x[o]      = t0 > 0.f ? t0 : expm1f(t0);
        x[16 + o] = t1 > 0.f ? t1 : expm1f(t1);
    }
    float z0 = 0.f, z1 = 0.f;
#pragma unroll
    for (int j = 0; j < 32; ++j) {
        z0 += x[j] * fc2[2 * j];
        z1 += x[j] * fc2[2 * j + 1];
    }
    z2[n] = make_float2(z0, z1);                      // normal store: z2 L2-hot for gat2
}

// layer-2 edge pass: stream meta (from rec), gather z2[sn]; padded planes; exp shift 48
__launch_bounds__(512)
__global__ void k_gat2(const uvec4* __restrict__ rec, const unsigned* __restrict__ cur,
                       const float2* __restrict__ z2, const float* __restrict__ attn2,
                       float* __restrict__ acc2c) {
    __shared__ float acc[3 * PL];
    __shared__ float cd[BNODES];
    int b = blockIdx.x;
    int nodebase = b << BSHIFT;
    int nn = min(BNODES, NN - nodebase);
    float a0 = attn2[0], a1 = attn2[1], a2 = attn2[2], a3 = attn2[3];
    for (int i = threadIdx.x; i < 3 * PL; i += 512) acc[i] = 0.f;
    for (int i = threadIdx.x; i < nn; i += 512) {
        float2 zd = z2[nodebase + i];
        cd[i] = fmaf(zd.x, a2, zd.y * a3);
    }
    __syncthreads();
    int cnt = min((int)cur[b], CAP);
    const uvec4* pr = rec + (size_t)b * CAP;
#pragma unroll 4
    for (int i = threadIdx.x; i < cnt; i += 512) {
        uvec4 r = __builtin_nontemporal_load(pr + i);
        int sn = r[0] & 0x3FFFF, dl = r[0] >> 18;
        float2 zs = z2[sn];                            // the remaining random gather
        float e = fmaf(zs.x, a0, fmaf(zs.y, a1, cd[dl]));
        e = e >= 0.f ? e : 0.01f * e;
        float ex = __expf(e - 48.f);   // cancels in softmax; e<=~88, den>=deg*e^-49
        ds_faddf(&acc[0 * PL + dl], ex);
        ds_faddf(&acc[1 * PL + dl], ex * zs.x);
        ds_faddf(&acc[2 * PL + dl], ex * zs.y);
    }
    asm volatile("s_waitcnt lgkmcnt(0)" ::: "memory");
    __syncthreads();
    for (int w = threadIdx.x; w < 3 * BNODES; w += 512) {
        int j = w >> BSHIFT, k = w & (BNODES - 1);
        if (k < nn) acc2c[(size_t)j * NN + nodebase + k] = acc[j * PL + k];
    }
}

// x2 = num/den; f64 dot with mlp_w; block reduce; f64 atomic
__global__ void k_final(const float* __restrict__ acc2c, const float* __restrict__ mlp_w,
                        double* __restrict__ dacc) {
    int n = blockIdx.x * blockDim.x + threadIdx.x;
    double v = 0.0;
    if (n < NN) {
        float den = acc2c[(size_t)0 * NN + n];
        float n0  = acc2c[(size_t)1 * NN + n];
        float n1  = acc2c[(size_t)2 * NN + n];
        float x0 = den > 0.f ? n0 / den : 0.f;
        float x1 = den > 0.f ? n1 / den : 0.f;
        v = (double)x0 * (double)__builtin_nontemporal_load(&mlp_w[2 * n]) +
            (double)x1 * (double)__builtin_nontemporal_load(&mlp_w[2 * n + 1]);
    }
    for (int off = 32; off > 0; off >>= 1) v += __shfl_down(v, off);
    __shared__ double sm[4];
    int lane = threadIdx.x & 63, wid = threadIdx.x >> 6;
    if (lane == 0) sm[wid] = v;
    __syncthreads();
    if (threadIdx.x == 0) {
        double sum = sm[0] + sm[1] + sm[2] + sm[3];
        unsafeAtomicAdd(dacc, sum);
    }
}

__global__ void k_out(const double* __restrict__ dacc, const float* __restrict__ mlp_b,
                      float* __restrict__ out) {
    double logit = dacc[0] + (double)mlp_b[0];
    out[0] = (float)(1.0 / (1.0 + exp(-logit)));
}

extern "C" void kernel_launch(void* const* d_in, const int* in_sizes, int n_in,
                              void* d_out, int out_size, void* d_ws, size_t ws_size,
                              hipStream_t stream) {
    const float* h     = (const float*)d_in[0];
    const int*   src   = (const int*)d_in[1];
    const int*   dst   = (const int*)d_in[2];
    const float* fc1   = (const float*)d_in[3];
    const float* attn1 = (const float*)d_in[4];
    const float* fc2   = (const float*)d_in[5];
    const float* attn2 = (const float*)d_in[6];
    const float* mlp_w = (const float*)d_in[7];
    const float* mlp_b = (const float*)d_in[8];
    float* out = (float*)d_out;

    unsigned* ws   = (unsigned*)d_ws;
    double*   dacc = (double*)d_ws;
    float*    uv   = (float*)(ws + W_UV);
    unsigned* cur  = ws + W_CUR;
    uvec4*    rec  = (uvec4*)(ws + W_REC);
    float*    accc = (float*)(ws + W_ACC);   // 6 planes layer1; first 3 reused layer2
    float2*   z2   = (float2*)(ws + W_Z2);

    hipLaunchKernelGGL(k_init, dim3(4), dim3(256), 0, stream, ws);
    hipLaunchKernelGGL(k_prep, dim3(1), dim3(64), 0, stream, fc1, attn1, uv);
    hipLaunchKernelGGL(k_scatter, dim3(NBLK_SC), dim3(256), 0, stream,
                       src, dst, (const float2*)h, rec, cur);
    hipLaunchKernelGGL(k_gat1, dim3(NB), dim3(512), 0, stream,
                       rec, cur, (const float2*)h, uv, accc);
    hipLaunchKernelGGL(k_node1, dim3((NN + 255) / 256), dim3(256), 0, stream,
                       accc, fc1, fc2, z2);
    hipLaunchKernelGGL(k_gat2, dim3(NB), dim3(512), 0, stream,
                       rec, cur, (const float2*)z2, attn2, accc);
    hipLaunchKernelGGL(k_final, dim3((NN + 255) / 256), dim3(256), 0, stream,
                       accc, mlp_w, dacc);
    hipLaunchKernelGGL(k_out, dim3(1), dim3(1), 0, stream, dacc, mlp_b, out);
}

// Round 11
// 432.020 us; speedup vs baseline: 1.7662x; 1.4084x over previous
//
#include <hip/hip_runtime.h>
#include <hip/hip_bf16.h>
#include <math.h>

#define NN 200000
#define NE 6400000

#define BSHIFT 7
#define BNODES 128                     // nodes per bucket
#define NB 1563                        // ceil(NN / 128); last bucket has 64 nodes
#define CAP 4608                       // bucket capacity (mean 4096, sigma 64 -> +8 sigma)
#define NBLK_SC 512
#define CHUNK (NE / NBLK_SC)           // 12500

// ---- workspace layout (4-byte words) ----
#define W_DACC 0                       // double (2 words)
#define W_UV   4                       // 8 floats
#define W_CUR  16                      // NB uints
#define W_NOFF 2048                    // NN uints: absolute record-slot offset per node
#define W_NCNT (W_NOFF + NN)           // NN uints: record count per node
#define W_REC  (W_NCNT + NN)           // 3*NB*CAP u32: 12B records {meta, hx, hy}; sorted in place
#define W_ACC  (W_REC + 3*NB*CAP)      // 6*NN f32 planar [j*NN+n]; layer2 reuses 3 planes
#define W_Z2   (W_ACC + 6*NN)          // 2*NN f32 (float2/node)
#define W_TOTAL (W_Z2 + 2*NN)          // ~23.6M words = 94.4 MB

__global__ void k_init(unsigned* __restrict__ ws) {
    int t = blockIdx.x * blockDim.x + threadIdx.x;
    if (t == 0) *(double*)ws = 0.0;
    if (t < NB) ws[W_CUR + t] = 0u;
}

// u_i(h) = sum_o fc1[h][i][o]*attn1[h][o];  v_i(h) = sum_o fc1[h][i][o]*attn1[h][16+o]
__global__ void k_prep(const float* __restrict__ fc1, const float* __restrict__ attn1,
                       float* __restrict__ uv) {
    int t = threadIdx.x;
    if (t < 8) {
        int h = t >> 2, r = t & 3, i = r & 1, isv = r >> 1;
        double s = 0.0;
        for (int o = 0; o < 16; ++o)
            s += (double)fc1[h * 32 + i * 16 + o] * (double)attn1[h * 32 + isv * 16 + o];
        uv[t] = (float)s;
    }
}

// radix partition by dst bucket; embeds h[src] in a 12B record {meta, hx, hy},
// meta = sn(18b) | dl(7b)<<18.
__global__ void k_scatter(const int* __restrict__ src, const int* __restrict__ dst,
                          const float2* __restrict__ h,
                          unsigned* __restrict__ rec, unsigned* __restrict__ cur) {
    __shared__ unsigned cnt[NB], gbase[NB], rk[NB];   // 18.8 KB
    for (int i = threadIdx.x; i < NB; i += blockDim.x) { cnt[i] = 0u; rk[i] = 0u; }
    __syncthreads();
    int beg = blockIdx.x * CHUNK, end = beg + CHUNK;
    for (int i = beg + threadIdx.x; i < end; i += blockDim.x)
        atomicAdd(&cnt[(unsigned)dst[i] >> BSHIFT], 1u);
    __syncthreads();
    for (int i = threadIdx.x; i < NB; i += blockDim.x)
        gbase[i] = cnt[i] ? atomicAdd(&cur[i], cnt[i]) : 0u;
    __syncthreads();
    for (int i = beg + threadIdx.x; i < end; i += blockDim.x) {
        int d = dst[i];                                   // L2-hot (primed by histogram)
        int b = d >> BSHIFT;
        unsigned rank = atomicAdd(&rk[b], 1u);
        unsigned slot = gbase[b] + rank;
        if (slot < CAP) {
            int sn = __builtin_nontemporal_load(src + i);
            float2 hs = h[sn];                            // the one random gather per edge
            size_t w = ((size_t)b * CAP + slot) * 3;
            rec[w]     = (unsigned)sn | ((unsigned)(d & (BNODES - 1)) << 18);
            rec[w + 1] = __float_as_uint(hs.x);
            rec[w + 2] = __float_as_uint(hs.y);
        }
    }
}

// counting sort by node within each bucket; emits per-node offsets/counts.
// One block per bucket; whole bucket staged in LDS; records rewritten sorted.
__launch_bounds__(256)
__global__ void k_sort(unsigned* __restrict__ rec, const unsigned* __restrict__ cur,
                       unsigned* __restrict__ nodeoff, unsigned* __restrict__ nodecnt) {
    __shared__ unsigned raw[3 * CAP];                     // 55.3 KB
    __shared__ unsigned hist[BNODES], base[BNODES], cursor[BNODES], scan[BNODES];
    int b = blockIdx.x;
    size_t boff = (size_t)b * CAP;
    int cnt = min((int)cur[b], CAP);
    for (int i = threadIdx.x; i < BNODES; i += 256) hist[i] = 0u;
    for (int i = threadIdx.x; i < cnt; i += 256) {        // coalesced 12B loads
        size_t w = (boff + i) * 3;
        raw[3 * i]     = rec[w];
        raw[3 * i + 1] = rec[w + 1];
        raw[3 * i + 2] = rec[w + 2];
    }
    __syncthreads();
    for (int i = threadIdx.x; i < cnt; i += 256)
        atomicAdd(&hist[raw[3 * i] >> 18], 1u);           // 1 LDS atomic / edge
    __syncthreads();
    if (threadIdx.x < BNODES) scan[threadIdx.x] = hist[threadIdx.x];
    __syncthreads();
    for (int d = 1; d < BNODES; d <<= 1) {                // Hillis-Steele inclusive scan
        unsigned v = 0u;
        if (threadIdx.x < BNODES && (int)threadIdx.x >= d) v = scan[threadIdx.x - d];
        __syncthreads();
        if (threadIdx.x < BNODES) scan[threadIdx.x] += v;
        __syncthreads();
    }
    if (threadIdx.x < BNODES) {
        unsigned ex = scan[threadIdx.x] - hist[threadIdx.x];
        base[threadIdx.x] = ex;
        cursor[threadIdx.x] = ex;
    }
    __syncthreads();
    int nb = b * BNODES;
    int nn = min(BNODES, NN - nb);
    if ((int)threadIdx.x < nn) {
        nodeoff[nb + threadIdx.x] = (unsigned)(boff + base[threadIdx.x]);
        nodecnt[nb + threadIdx.x] = hist[threadIdx.x];
    }
    for (int i = threadIdx.x; i < cnt; i += 256) {        // 1 LDS atomic / edge
        unsigned m = raw[3 * i];
        unsigned r = atomicAdd(&cursor[m >> 18], 1u);
        size_t w = (boff + r) * 3;                        // in-place region (LDS-staged)
        rec[w]     = m;
        rec[w + 1] = raw[3 * i + 1];
        rec[w + 2] = raw[3 * i + 2];
    }
}

// layer-1: thread-per-node, ZERO atomics, register accumulation over sorted segment.
__global__ void k_gat1(const unsigned* __restrict__ rec, const unsigned* __restrict__ nodeoff,
                       const unsigned* __restrict__ nodecnt, const float2* __restrict__ h,
                       const float* __restrict__ uv, float* __restrict__ accc) {
    int n = blockIdx.x * blockDim.x + threadIdx.x;
    if (n >= NN) return;
    float u00 = uv[0], u10 = uv[1], v00 = uv[2], v10 = uv[3];
    float u01 = uv[4], u11 = uv[5], v01 = uv[6], v11 = uv[7];
    float2 hd = h[n];
    float c0 = fmaf(hd.x, v00, hd.y * v10);
    float c1 = fmaf(hd.x, v01, hd.y * v11);
    unsigned off = nodeoff[n];
    int cnt = (int)nodecnt[n];
    float s0 = 0.f, s1 = 0.f, s2 = 0.f, s3 = 0.f, s4 = 0.f, s5 = 0.f;
#pragma unroll 2
    for (int k = 0; k < cnt; ++k) {
        size_t w = ((size_t)off + k) * 3;
        float hx = __uint_as_float(rec[w + 1]);
        float hy = __uint_as_float(rec[w + 2]);
        float e0 = fmaf(hx, u00, fmaf(hy, u10, c0));
        float e1 = fmaf(hx, u01, fmaf(hy, u11, c1));
        e0 = e0 >= 0.f ? e0 : 0.01f * e0;
        e1 = e1 >= 0.f ? e1 : 0.01f * e1;
        float ex0 = __expf(e0);
        float ex1 = __expf(e1);
        s0 += ex0; s1 += ex0 * hx; s2 += ex0 * hy;
        s3 += ex1; s4 += ex1 * hx; s5 += ex1 * hy;
    }
    accc[(size_t)0 * NN + n] = s0;
    accc[(size_t)1 * NN + n] = s1;
    accc[(size_t)2 * NN + n] = s2;
    accc[(size_t)3 * NN + n] = s3;
    accc[(size_t)4 * NN + n] = s4;
    accc[(size_t)5 * NN + n] = s5;
}

// finalize layer1 (softmax div + elu), z2 = x @ fc2
__global__ void k_node1(const float* __restrict__ accc, const float* __restrict__ fc1,
                        const float* __restrict__ fc2, float2* __restrict__ z2) {
    int n = blockIdx.x * blockDim.x + threadIdx.x;
    if (n >= NN) return;
    float a[6];
#pragma unroll
    for (int j = 0; j < 6; ++j) a[j] = accc[(size_t)j * NN + n];
    float den0 = a[0], A0 = a[1], B0 = a[2];
    float den1 = a[3], A1 = a[4], B1 = a[5];
    float x[32];
#pragma unroll
    for (int o = 0; o < 16; ++o) {
        float t0 = den0 > 0.f ? (A0 * fc1[o]      + B0 * fc1[16 + o]) / den0 : 0.f;
        float t1 = den1 > 0.f ? (A1 * fc1[32 + o] + B1 * fc1[48 + o]) / den1 : 0.f;
        x[o]      = t0 > 0.f ? t0 : expm1f(t0);
        x[16 + o] = t1 > 0.f ? t1 : expm1f(t1);
    }
    float z0 = 0.f, z1 = 0.f;
#pragma unroll
    for (int j = 0; j < 32; ++j) {
        z0 += x[j] * fc2[2 * j];
        z1 += x[j] * fc2[2 * j + 1];
    }
    z2[n] = make_float2(z0, z1);
}

// layer-2: thread-per-node, ZERO atomics; z2[sn] gathers are L2-resident (1.6 MB).
__global__ void k_gat2(const unsigned* __restrict__ rec, const unsigned* __restrict__ nodeoff,
                       const unsigned* __restrict__ nodecnt, const float2* __restrict__ z2,
                       const float* __restrict__ attn2, float* __restrict__ acc2c) {
    int n = blockIdx.x * blockDim.x + threadIdx.x;
    if (n >= NN) return;
    float a0 = attn2[0], a1 = attn2[1], a2 = attn2[2], a3 = attn2[3];
    float2 zd = z2[n];
    float cd = fmaf(zd.x, a2, zd.y * a3);
    unsigned off = nodeoff[n];
    int cnt = (int)nodecnt[n];
    float s0 = 0.f, s1 = 0.f, s2 = 0.f;
#pragma unroll 4
    for (int k = 0; k < cnt; ++k) {
        unsigned m = rec[((size_t)off + k) * 3];
        float2 zs = z2[m & 0x3FFFF];
        float e = fmaf(zs.x, a0, fmaf(zs.y, a1, cd));
        e = e >= 0.f ? e : 0.01f * e;
        float ex = __expf(e - 48.f);   // const shift cancels in softmax; e<=~88, den>=deg*e^-49
        s0 += ex; s1 += ex * zs.x; s2 += ex * zs.y;
    }
    acc2c[(size_t)0 * NN + n] = s0;
    acc2c[(size_t)1 * NN + n] = s1;
    acc2c[(size_t)2 * NN + n] = s2;
}

// x2 = num/den; f64 dot with mlp_w; block reduce; f64 atomic
__global__ void k_final(const float* __restrict__ acc2c, const float* __restrict__ mlp_w,
                        double* __restrict__ dacc) {
    int n = blockIdx.x * blockDim.x + threadIdx.x;
    double v = 0.0;
    if (n < NN) {
        float den = acc2c[(size_t)0 * NN + n];
        float n0  = acc2c[(size_t)1 * NN + n];
        float n1  = acc2c[(size_t)2 * NN + n];
        float x0 = den > 0.f ? n0 / den : 0.f;
        float x1 = den > 0.f ? n1 / den : 0.f;
        v = (double)x0 * (double)mlp_w[2 * n] + (double)x1 * (double)mlp_w[2 * n + 1];
    }
    for (int off = 32; off > 0; off >>= 1) v += __shfl_down(v, off);
    __shared__ double sm[4];
    int lane = threadIdx.x & 63, wid = threadIdx.x >> 6;
    if (lane == 0) sm[wid] = v;
    __syncthreads();
    if (threadIdx.x == 0) {
        double sum = sm[0] + sm[1] + sm[2] + sm[3];
        unsafeAtomicAdd(dacc, sum);
    }
}

__global__ void k_out(const double* __restrict__ dacc, const float* __restrict__ mlp_b,
                      float* __restrict__ out) {
    double logit = dacc[0] + (double)mlp_b[0];
    out[0] = (float)(1.0 / (1.0 + exp(-logit)));
}

extern "C" void kernel_launch(void* const* d_in, const int* in_sizes, int n_in,
                              void* d_out, int out_size, void* d_ws, size_t ws_size,
                              hipStream_t stream) {
    const float* h     = (const float*)d_in[0];
    const int*   src   = (const int*)d_in[1];
    const int*   dst   = (const int*)d_in[2];
    const float* fc1   = (const float*)d_in[3];
    const float* attn1 = (const float*)d_in[4];
    const float* fc2   = (const float*)d_in[5];
    const float* attn2 = (const float*)d_in[6];
    const float* mlp_w = (const float*)d_in[7];
    const float* mlp_b = (const float*)d_in[8];
    float* out = (float*)d_out;

    unsigned* ws      = (unsigned*)d_ws;
    double*   dacc    = (double*)d_ws;
    float*    uv      = (float*)(ws + W_UV);
    unsigned* cur     = ws + W_CUR;
    unsigned* nodeoff = ws + W_NOFF;
    unsigned* nodecnt = ws + W_NCNT;
    unsigned* rec     = ws + W_REC;
    float*    accc    = (float*)(ws + W_ACC);   // 6 planes layer1; first 3 reused layer2
    float2*   z2      = (float2*)(ws + W_Z2);

    const int NG = (NN + 255) / 256;            // 782

    hipLaunchKernelGGL(k_init, dim3(7), dim3(256), 0, stream, ws);
    hipLaunchKernelGGL(k_prep, dim3(1), dim3(64), 0, stream, fc1, attn1, uv);
    hipLaunchKernelGGL(k_scatter, dim3(NBLK_SC), dim3(256), 0, stream,
                       src, dst, (const float2*)h, rec, cur);
    hipLaunchKernelGGL(k_sort, dim3(NB), dim3(256), 0, stream,
                       rec, cur, nodeoff, nodecnt);
    hipLaunchKernelGGL(k_gat1, dim3(NG), dim3(256), 0, stream,
                       rec, nodeoff, nodecnt, (const float2*)h, uv, accc);
    hipLaunchKernelGGL(k_node1, dim3(NG), dim3(256), 0, stream, accc, fc1, fc2, z2);
    hipLaunchKernelGGL(k_gat2, dim3(NG), dim3(256), 0, stream,
                       rec, nodeoff, nodecnt, (const float2*)z2, attn2, accc);
    hipLaunchKernelGGL(k_final, dim3(NG), dim3(256), 0, stream, accc, mlp_w, dacc);
    hipLaunchKernelGGL(k_out, dim3(1), dim3(1), 0, stream, dacc, mlp_b, out);
}

// Round 12
// 390.182 us; speedup vs baseline: 1.9556x; 1.1072x over previous
//
#include <hip/hip_runtime.h>
#include <hip/hip_bf16.h>
#include <math.h>

#define NN 200000
#define NE 6400000

#define BSHIFT 7
#define BNODES 128                     // nodes per bucket
#define NB 1563                        // ceil(NN / 128); last bucket has 64 nodes
#define CAP 4608                       // bucket capacity (mean 4096, sigma 64 -> +8 sigma)
#define NBLK_SC 512
#define SCT 1024                       // scatter block threads (16 waves)
#define CHUNK (NE / NBLK_SC)           // 12500

// ---- workspace layout (4-byte words) ----
#define W_DACC 0                       // double (2 words)
#define W_UV   4                       // 8 floats
#define W_CUR  16                      // NB uints
#define W_NOFF 2048                    // NN uints: absolute record-slot offset per node
#define W_NCNT (W_NOFF + NN)           // NN uints: record count per node
#define W_REC  (W_NCNT + NN)           // 3*NB*CAP u32: 12B records {meta, hx, hy}; sorted in place
#define W_ACC  (W_REC + 3*NB*CAP)      // 6*NN f32 planar [j*NN+n]; layer2 reuses 3 planes
#define W_Z2   (W_ACC + 6*NN)          // 2*NN f32 (float2/node)
#define W_TOTAL (W_Z2 + 2*NN)          // ~23.6M words = 94.4 MB

__global__ void k_init(unsigned* __restrict__ ws) {
    int t = blockIdx.x * blockDim.x + threadIdx.x;
    if (t == 0) *(double*)ws = 0.0;
    if (t < NB) ws[W_CUR + t] = 0u;
}

// u_i(h) = sum_o fc1[h][i][o]*attn1[h][o];  v_i(h) = sum_o fc1[h][i][o]*attn1[h][16+o]
__global__ void k_prep(const float* __restrict__ fc1, const float* __restrict__ attn1,
                       float* __restrict__ uv) {
    int t = threadIdx.x;
    if (t < 8) {
        int h = t >> 2, r = t & 3, i = r & 1, isv = r >> 1;
        double s = 0.0;
        for (int o = 0; o < 16; ++o)
            s += (double)fc1[h * 32 + i * 16 + o] * (double)attn1[h * 32 + isv * 16 + o];
        uv[t] = (float)s;
    }
}

// radix partition by dst bucket; embeds h[src] in a 12B record {meta, hx, hy}.
// 1024-thread blocks: 16 waves each, 512 blocks -> 32 waves/CU budget.
__launch_bounds__(SCT)
__global__ void k_scatter(const int* __restrict__ src, const int* __restrict__ dst,
                          const float2* __restrict__ h,
                          unsigned* __restrict__ rec, unsigned* __restrict__ cur) {
    __shared__ unsigned cnt[NB], gbase[NB];           // 12.5 KB
    for (int i = threadIdx.x; i < NB; i += SCT) cnt[i] = 0u;
    __syncthreads();
    int beg = blockIdx.x * CHUNK, end = beg + CHUNK;
    for (int i = beg + threadIdx.x; i < end; i += SCT)
        atomicAdd(&cnt[(unsigned)dst[i] >> BSHIFT], 1u);
    __syncthreads();
    for (int i = threadIdx.x; i < NB; i += SCT)
        gbase[i] = cnt[i] ? atomicAdd(&cur[i], cnt[i]) : 0u;
    __syncthreads();
    for (int i = threadIdx.x; i < NB; i += SCT) cnt[i] = 0u;   // reuse cnt as cursor
    __syncthreads();
    for (int i = beg + threadIdx.x; i < end; i += SCT) {
        int d = dst[i];                                   // L2-hot (primed by histogram)
        int b = d >> BSHIFT;
        unsigned rank = atomicAdd(&cnt[b], 1u);
        unsigned slot = gbase[b] + rank;
        if (slot < CAP) {
            int sn = __builtin_nontemporal_load(src + i);
            float2 hs = h[sn];                            // the one random gather per edge
            size_t w = ((size_t)b * CAP + slot) * 3;
            rec[w]     = (unsigned)sn | ((unsigned)(d & (BNODES - 1)) << 18);
            rec[w + 1] = __float_as_uint(hs.x);
            rec[w + 2] = __float_as_uint(hs.y);
        }
    }
}

// counting sort by node within each bucket; emits per-node offsets/counts.
// One block per bucket; whole bucket staged in LDS; records rewritten sorted.
__launch_bounds__(256)
__global__ void k_sort(unsigned* __restrict__ rec, const unsigned* __restrict__ cur,
                       unsigned* __restrict__ nodeoff, unsigned* __restrict__ nodecnt) {
    __shared__ unsigned raw[3 * CAP];                     // 55.3 KB
    __shared__ unsigned hist[BNODES], base[BNODES], cursor[BNODES], scan[BNODES];
    int b = blockIdx.x;
    size_t boff = (size_t)b * CAP;
    int cnt = min((int)cur[b], CAP);
    for (int i = threadIdx.x; i < BNODES; i += 256) hist[i] = 0u;
    for (int i = threadIdx.x; i < cnt; i += 256) {        // coalesced 12B loads
        size_t w = (boff + i) * 3;
        raw[3 * i]     = rec[w];
        raw[3 * i + 1] = rec[w + 1];
        raw[3 * i + 2] = rec[w + 2];
    }
    __syncthreads();
    for (int i = threadIdx.x; i < cnt; i += 256)
        atomicAdd(&hist[raw[3 * i] >> 18], 1u);           // 1 LDS atomic / edge
    __syncthreads();
    if (threadIdx.x < BNODES) scan[threadIdx.x] = hist[threadIdx.x];
    __syncthreads();
    for (int d = 1; d < BNODES; d <<= 1) {                // Hillis-Steele inclusive scan
        unsigned v = 0u;
        if (threadIdx.x < BNODES && (int)threadIdx.x >= d) v = scan[threadIdx.x - d];
        __syncthreads();
        if (threadIdx.x < BNODES) scan[threadIdx.x] += v;
        __syncthreads();
    }
    if (threadIdx.x < BNODES) {
        unsigned ex = scan[threadIdx.x] - hist[threadIdx.x];
        base[threadIdx.x] = ex;
        cursor[threadIdx.x] = ex;
    }
    __syncthreads();
    int nb = b * BNODES;
    int nn = min(BNODES, NN - nb);
    if ((int)threadIdx.x < nn) {
        nodeoff[nb + threadIdx.x] = (unsigned)(boff + base[threadIdx.x]);
        nodecnt[nb + threadIdx.x] = hist[threadIdx.x];
    }
    for (int i = threadIdx.x; i < cnt; i += 256) {        // 1 LDS atomic / edge
        unsigned m = raw[3 * i];
        unsigned r = atomicAdd(&cursor[m >> 18], 1u);
        size_t w = (boff + r) * 3;                        // in-place region (LDS-staged)
        rec[w]     = m;
        rec[w + 1] = raw[3 * i + 1];
        rec[w + 2] = raw[3 * i + 2];
    }
}

// layer-1: thread-per-node, ZERO atomics, register accumulation over sorted segment.
__global__ void k_gat1(const unsigned* __restrict__ rec, const unsigned* __restrict__ nodeoff,
                       const unsigned* __restrict__ nodecnt, const float2* __restrict__ h,
                       const float* __restrict__ uv, float* __restrict__ accc) {
    int n = blockIdx.x * blockDim.x + threadIdx.x;
    if (n >= NN) return;
    float u00 = uv[0], u10 = uv[1], v00 = uv[2], v10 = uv[3];
    float u01 = uv[4], u11 = uv[5], v01 = uv[6], v11 = uv[7];
    float2 hd = h[n];
    float c0 = fmaf(hd.x, v00, hd.y * v10);
    float c1 = fmaf(hd.x, v01, hd.y * v11);
    unsigned off = nodeoff[n];
    int cnt = (int)nodecnt[n];
    float s0 = 0.f, s1 = 0.f, s2 = 0.f, s3 = 0.f, s4 = 0.f, s5 = 0.f;
#pragma unroll 2
    for (int k = 0; k < cnt; ++k) {
        size_t w = ((size_t)off + k) * 3;
        float hx = __uint_as_float(rec[w + 1]);
        float hy = __uint_as_float(rec[w + 2]);
        float e0 = fmaf(hx, u00, fmaf(hy, u10, c0));
        float e1 = fmaf(hx, u01, fmaf(hy, u11, c1));
        e0 = e0 >= 0.f ? e0 : 0.01f * e0;
        e1 = e1 >= 0.f ? e1 : 0.01f * e1;
        float ex0 = __expf(e0);
        float ex1 = __expf(e1);
        s0 += ex0; s1 += ex0 * hx; s2 += ex0 * hy;
        s3 += ex1; s4 += ex1 * hx; s5 += ex1 * hy;
    }
    accc[(size_t)0 * NN + n] = s0;
    accc[(size_t)1 * NN + n] = s1;
    accc[(size_t)2 * NN + n] = s2;
    accc[(size_t)3 * NN + n] = s3;
    accc[(size_t)4 * NN + n] = s4;
    accc[(size_t)5 * NN + n] = s5;
}

// finalize layer1 (softmax div + elu), z2 = x @ fc2
__global__ void k_node1(const float* __restrict__ accc, const float* __restrict__ fc1,
                        const float* __restrict__ fc2, float2* __restrict__ z2) {
    int n = blockIdx.x * blockDim.x + threadIdx.x;
    if (n >= NN) return;
    float a[6];
#pragma unroll
    for (int j = 0; j < 6; ++j) a[j] = accc[(size_t)j * NN + n];
    float den0 = a[0], A0 = a[1], B0 = a[2];
    float den1 = a[3], A1 = a[4], B1 = a[5];
    float x[32];
#pragma unroll
    for (int o = 0; o < 16; ++o) {
        float t0 = den0 > 0.f ? (A0 * fc1[o]      + B0 * fc1[16 + o]) / den0 : 0.f;
        float t1 = den1 > 0.f ? (A1 * fc1[32 + o] + B1 * fc1[48 + o]) / den1 : 0.f;
        x[o]      = t0 > 0.f ? t0 : expm1f(t0);
        x[16 + o] = t1 > 0.f ? t1 : expm1f(t1);
    }
    float z0 = 0.f, z1 = 0.f;
#pragma unroll
    for (int j = 0; j < 32; ++j) {
        z0 += x[j] * fc2[2 * j];
        z1 += x[j] * fc2[2 * j + 1];
    }
    z2[n] = make_float2(z0, z1);
}

// layer-2: thread-per-node, ZERO atomics; z2[sn] gathers are L2-resident (1.6 MB).
__global__ void k_gat2(const unsigned* __restrict__ rec, const unsigned* __restrict__ nodeoff,
                       const unsigned* __restrict__ nodecnt, const float2* __restrict__ z2,
                       const float* __restrict__ attn2, float* __restrict__ acc2c) {
    int n = blockIdx.x * blockDim.x + threadIdx.x;
    if (n >= NN) return;
    float a0 = attn2[0], a1 = attn2[1], a2 = attn2[2], a3 = attn2[3];
    float2 zd = z2[n];
    float cd = fmaf(zd.x, a2, zd.y * a3);
    unsigned off = nodeoff[n];
    int cnt = (int)nodecnt[n];
    float s0 = 0.f, s1 = 0.f, s2 = 0.f;
#pragma unroll 4
    for (int k = 0; k < cnt; ++k) {
        unsigned m = rec[((size_t)off + k) * 3];
        float2 zs = z2[m & 0x3FFFF];
        float e = fmaf(zs.x, a0, fmaf(zs.y, a1, cd));
        e = e >= 0.f ? e : 0.01f * e;
        float ex = __expf(e - 48.f);   // const shift cancels in softmax; e<=~88, den>=deg*e^-49
        s0 += ex; s1 += ex * zs.x; s2 += ex * zs.y;
    }
    acc2c[(size_t)0 * NN + n] = s0;
    acc2c[(size_t)1 * NN + n] = s1;
    acc2c[(size_t)2 * NN + n] = s2;
}

// x2 = num/den; f64 dot with mlp_w; block reduce; f64 atomic
__global__ void k_final(const float* __restrict__ acc2c, const float* __restrict__ mlp_w,
                        double* __restrict__ dacc) {
    int n = blockIdx.x * blockDim.x + threadIdx.x;
    double v = 0.0;
    if (n < NN) {
        float den = acc2c[(size_t)0 * NN + n];
        float n0  = acc2c[(size_t)1 * NN + n];
        float n1  = acc2c[(size_t)2 * NN + n];
        float x0 = den > 0.f ? n0 / den : 0.f;
        float x1 = den > 0.f ? n1 / den : 0.f;
        v = (double)x0 * (double)mlp_w[2 * n] + (double)x1 * (double)mlp_w[2 * n + 1];
    }
    for (int off = 32; off > 0; off >>= 1) v += __shfl_down(v, off);
    __shared__ double sm[4];
    int lane = threadIdx.x & 63, wid = threadIdx.x >> 6;
    if (lane == 0) sm[wid] = v;
    __syncthreads();
    if (threadIdx.x == 0) {
        double sum = sm[0] + sm[1] + sm[2] + sm[3];
        unsafeAtomicAdd(dacc, sum);
    }
}

__global__ void k_out(const double* __restrict__ dacc, const float* __restrict__ mlp_b,
                      float* __restrict__ out) {
    double logit = dacc[0] + (double)mlp_b[0];
    out[0] = (float)(1.0 / (1.0 + exp(-logit)));
}

extern "C" void kernel_launch(void* const* d_in, const int* in_sizes, int n_in,
                              void* d_out, int out_size, void* d_ws, size_t ws_size,
                              hipStream_t stream) {
    const float* h     = (const float*)d_in[0];
    const int*   src   = (const int*)d_in[1];
    const int*   dst   = (const int*)d_in[2];
    const float* fc1   = (const float*)d_in[3];
    const float* attn1 = (const float*)d_in[4];
    const float* fc2   = (const float*)d_in[5];
    const float* attn2 = (const float*)d_in[6];
    const float* mlp_w = (const float*)d_in[7];
    const float* mlp_b = (const float*)d_in[8];
    float* out = (float*)d_out;

    unsigned* ws      = (unsigned*)d_ws;
    double*   dacc    = (double*)d_ws;
    float*    uv      = (float*)(ws + W_UV);
    unsigned* cur     = ws + W_CUR;
    unsigned* nodeoff = ws + W_NOFF;
    unsigned* nodecnt = ws + W_NCNT;
    unsigned* rec     = ws + W_REC;
    float*    accc    = (float*)(ws + W_ACC);   // 6 planes layer1; first 3 reused layer2
    float2*   z2      = (float2*)(ws + W_Z2);

    const int NG = (NN + 255) / 256;            // 782

    hipLaunchKernelGGL(k_init, dim3(7), dim3(256), 0, stream, ws);
    hipLaunchKernelGGL(k_prep, dim3(1), dim3(64), 0, stream, fc1, attn1, uv);
    hipLaunchKernelGGL(k_scatter, dim3(NBLK_SC), dim3(SCT), 0, stream,
                       src, dst, (const float2*)h, rec, cur);
    hipLaunchKernelGGL(k_sort, dim3(NB), dim3(256), 0, stream,
                       rec, cur, nodeoff, nodecnt);
    hipLaunchKernelGGL(k_gat1, dim3(NG), dim3(256), 0, stream,
                       rec, nodeoff, nodecnt, (const float2*)h, uv, accc);
    hipLaunchKernelGGL(k_node1, dim3(NG), dim3(256), 0, stream, accc, fc1, fc2, z2);
    hipLaunchKernelGGL(k_gat2, dim3(NG), dim3(256), 0, stream,
                       rec, nodeoff, nodecnt, (const float2*)z2, attn2, accc);
    hipLaunchKernelGGL(k_final, dim3(NG), dim3(256), 0, stream, accc, mlp_w, dacc);
    hipLaunchKernelGGL(k_out, dim3(1), dim3(1), 0, stream, dacc, mlp_b, out);
}

// Round 13
// 343.216 us; speedup vs baseline: 2.2232x; 1.1368x over previous
//
#include <hip/hip_runtime.h>
#include <hip/hip_bf16.h>
#include <math.h>

#define NN 200000
#define NE 6400000

#define BSHIFT 9
#define BNODES 512                     // nodes per bucket
#define NB 391                         // ceil(NN / 512); last bucket has 320 nodes
#define CAP 17408                      // = 17*1024; mean 16384, sigma ~128 -> +8 sigma
#define NBLK_SC 256
#define SCT 1024                       // scatter block threads (16 waves)
#define CHUNK (NE / NBLK_SC)           // 25000

// ---- workspace layout (4-byte words) ----
#define W_DACC 0                       // double (2 words)
#define W_UV   4                       // 8 floats
#define W_CUR  16                      // NB uints
#define W_NOFF 2048                    // NN uints: absolute record-slot offset per node
#define W_NCNT (W_NOFF + NN)           // NN uints: record count per node
#define W_REC  (W_NCNT + NN)           // 3*NB*CAP u32: 12B records {meta, hx, hy}; sorted in place
#define W_ACC  (W_REC + 3*NB*CAP)      // 6*NN f32 planar [j*NN+n]; layer2 reuses 3 planes
#define W_Z2   (W_ACC + 6*NN)          // 2*NN f32 (float2/node)
#define W_TOTAL (W_Z2 + 2*NN)          // ~22.4M words = 89.8 MB

__global__ void k_init(unsigned* __restrict__ ws) {
    int t = blockIdx.x * blockDim.x + threadIdx.x;
    if (t == 0) *(double*)ws = 0.0;
    if (t < NB) ws[W_CUR + t] = 0u;
}

// u_i(h) = sum_o fc1[h][i][o]*attn1[h][o];  v_i(h) = sum_o fc1[h][i][o]*attn1[h][16+o]
__global__ void k_prep(const float* __restrict__ fc1, const float* __restrict__ attn1,
                       float* __restrict__ uv) {
    int t = threadIdx.x;
    if (t < 8) {
        int h = t >> 2, r = t & 3, i = r & 1, isv = r >> 1;
        double s = 0.0;
        for (int o = 0; o < 16; ++o)
            s += (double)fc1[h * 32 + i * 16 + o] * (double)attn1[h * 32 + isv * 16 + o];
        uv[t] = (float)s;
    }
}

// radix partition by dst bucket; embeds h[src] in a 12B record {meta, hx, hy},
// meta = sn(18b) | dl(9b)<<18. 256 blocks -> ~64-record (768B) runs per bucket
// per block: full-line ownership kills write-allocate amplification.
__launch_bounds__(SCT)
__global__ void k_scatter(const int* __restrict__ src, const int* __restrict__ dst,
                          const float2* __restrict__ h,
                          unsigned* __restrict__ rec, unsigned* __restrict__ cur) {
    __shared__ unsigned cnt[NB], gbase[NB];           // 3.1 KB
    for (int i = threadIdx.x; i < NB; i += SCT) cnt[i] = 0u;
    __syncthreads();
    int beg = blockIdx.x * CHUNK, end = beg + CHUNK;
    for (int i = beg + threadIdx.x; i < end; i += SCT)
        atomicAdd(&cnt[(unsigned)dst[i] >> BSHIFT], 1u);
    __syncthreads();
    for (int i = threadIdx.x; i < NB; i += SCT)
        gbase[i] = cnt[i] ? atomicAdd(&cur[i], cnt[i]) : 0u;
    __syncthreads();
    for (int i = threadIdx.x; i < NB; i += SCT) cnt[i] = 0u;   // reuse cnt as cursor
    __syncthreads();
    for (int i = beg + threadIdx.x; i < end; i += SCT) {
        int d = dst[i];                                   // L2-hot (primed by histogram)
        int b = d >> BSHIFT;
        unsigned rank = atomicAdd(&cnt[b], 1u);
        unsigned slot = gbase[b] + rank;
        if (slot < CAP) {
            int sn = __builtin_nontemporal_load(src + i);
            float2 hs = h[sn];                            // the one random gather per edge
            size_t w = ((size_t)b * CAP + slot) * 3;
            rec[w]     = (unsigned)sn | ((unsigned)(d & (BNODES - 1)) << 18);
            rec[w + 1] = __float_as_uint(hs.x);
            rec[w + 2] = __float_as_uint(hs.y);
        }
    }
}

// in-place counting sort by node within each bucket, records staged in REGISTERS
// (17 statically-indexed records/thread); LDS only for hist/scan/cursor.
__launch_bounds__(1024)
__global__ void k_sort(unsigned* __restrict__ rec, const unsigned* __restrict__ cur,
                       unsigned* __restrict__ nodeoff, unsigned* __restrict__ nodecnt) {
    __shared__ unsigned hist[BNODES], scan[BNODES], cursor[BNODES];   // 6 KB
    int b = blockIdx.x;
    int t = threadIdx.x;
    size_t boff = (size_t)b * CAP;
    int cnt = min((int)cur[b], CAP);
    for (int i = t; i < BNODES; i += 1024) hist[i] = 0u;
    __syncthreads();
    unsigned rm[17], rx[17], ry[17];
#pragma unroll
    for (int k = 0; k < 17; ++k) {
        int i = k * 1024 + t;
        rm[k] = 0xFFFFFFFFu;
        rx[k] = 0u; ry[k] = 0u;
        if (i < cnt) {
            size_t w = (boff + i) * 3;
            rm[k] = rec[w];
            rx[k] = rec[w + 1];
            ry[k] = rec[w + 2];
        }
    }
#pragma unroll
    for (int k = 0; k < 17; ++k)
        if (rm[k] != 0xFFFFFFFFu) atomicAdd(&hist[rm[k] >> 18], 1u);
    asm volatile("s_waitcnt vmcnt(0)" ::: "memory");   // all reads done before any write
    __syncthreads();
    if (t < BNODES) scan[t] = hist[t];
    __syncthreads();
    for (int d = 1; d < BNODES; d <<= 1) {             // Hillis-Steele inclusive scan
        unsigned v = 0u;
        if (t < BNODES && t >= d) v = scan[t - d];
        __syncthreads();
        if (t < BNODES) scan[t] += v;
        __syncthreads();
    }
    int nb = b * BNODES;
    int nn = min(BNODES, NN - nb);
    if (t < BNODES) {
        unsigned ex = scan[t] - hist[t];               // exclusive base
        cursor[t] = ex;
        if (t < nn) {
            nodeoff[nb + t] = (unsigned)boff + ex;
            nodecnt[nb + t] = hist[t];
        }
    }
    __syncthreads();
#pragma unroll
    for (int k = 0; k < 17; ++k) {
        if (rm[k] != 0xFFFFFFFFu) {
            unsigned r = atomicAdd(&cursor[rm[k] >> 18], 1u);
            size_t w = (boff + r) * 3;                 // in-place: reads all drained
            rec[w]     = rm[k];
            rec[w + 1] = rx[k];
            rec[w + 2] = ry[k];
        }
    }
}

// layer-1: thread-per-node, ZERO atomics, register accumulation over sorted segment.
__global__ void k_gat1(const unsigned* __restrict__ rec, const unsigned* __restrict__ nodeoff,
                       const unsigned* __restrict__ nodecnt, const float2* __restrict__ h,
                       const float* __restrict__ uv, float* __restrict__ accc) {
    int n = blockIdx.x * blockDim.x + threadIdx.x;
    if (n >= NN) return;
    float u00 = uv[0], u10 = uv[1], v00 = uv[2], v10 = uv[3];
    float u01 = uv[4], u11 = uv[5], v01 = uv[6], v11 = uv[7];
    float2 hd = h[n];
    float c0 = fmaf(hd.x, v00, hd.y * v10);
    float c1 = fmaf(hd.x, v01, hd.y * v11);
    unsigned off = nodeoff[n];
    int cnt = (int)nodecnt[n];
    float s0 = 0.f, s1 = 0.f, s2 = 0.f, s3 = 0.f, s4 = 0.f, s5 = 0.f;
#pragma unroll 2
    for (int k = 0; k < cnt; ++k) {
        size_t w = ((size_t)off + k) * 3;
        float hx = __uint_as_float(rec[w + 1]);
        float hy = __uint_as_float(rec[w + 2]);
        float e0 = fmaf(hx, u00, fmaf(hy, u10, c0));
        float e1 = fmaf(hx, u01, fmaf(hy, u11, c1));
        e0 = e0 >= 0.f ? e0 : 0.01f * e0;
        e1 = e1 >= 0.f ? e1 : 0.01f * e1;
        float ex0 = __expf(e0);
        float ex1 = __expf(e1);
        s0 += ex0; s1 += ex0 * hx; s2 += ex0 * hy;
        s3 += ex1; s4 += ex1 * hx; s5 += ex1 * hy;
    }
    accc[(size_t)0 * NN + n] = s0;
    accc[(size_t)1 * NN + n] = s1;
    accc[(size_t)2 * NN + n] = s2;
    accc[(size_t)3 * NN + n] = s3;
    accc[(size_t)4 * NN + n] = s4;
    accc[(size_t)5 * NN + n] = s5;
}

// finalize layer1 (softmax div + elu), z2 = x @ fc2
__global__ void k_node1(const float* __restrict__ accc, const float* __restrict__ fc1,
                        const float* __restrict__ fc2, float2* __restrict__ z2) {
    int n = blockIdx.x * blockDim.x + threadIdx.x;
    if (n >= NN) return;
    float a[6];
#pragma unroll
    for (int j = 0; j < 6; ++j) a[j] = accc[(size_t)j * NN + n];
    float den0 = a[0], A0 = a[1], B0 = a[2];
    float den1 = a[3], A1 = a[4], B1 = a[5];
    float x[32];
#pragma unroll
    for (int o = 0; o < 16; ++o) {
        float t0 = den0 > 0.f ? (A0 * fc1[o]      + B0 * fc1[16 + o]) / den0 : 0.f;
        float t1 = den1 > 0.f ? (A1 * fc1[32 + o] + B1 * fc1[48 + o]) / den1 : 0.f;
        x[o]      = t0 > 0.f ? t0 : expm1f(t0);
        x[16 + o] = t1 > 0.f ? t1 : expm1f(t1);
    }
    float z0 = 0.f, z1 = 0.f;
#pragma unroll
    for (int j = 0; j < 32; ++j) {
        z0 += x[j] * fc2[2 * j];
        z1 += x[j] * fc2[2 * j + 1];
    }
    z2[n] = make_float2(z0, z1);
}

// layer-2: thread-per-node, ZERO atomics; z2[sn] gathers are L2-resident (1.6 MB).
__global__ void k_gat2(const unsigned* __restrict__ rec, const unsigned* __restrict__ nodeoff,
                       const unsigned* __restrict__ nodecnt, const float2* __restrict__ z2,
                       const float* __restrict__ attn2, float* __restrict__ acc2c) {
    int n = blockIdx.x * blockDim.x + threadIdx.x;
    if (n >= NN) return;
    float a0 = attn2[0], a1 = attn2[1], a2 = attn2[2], a3 = attn2[3];
    float2 zd = z2[n];
    float cd = fmaf(zd.x, a2, zd.y * a3);
    unsigned off = nodeoff[n];
    int cnt = (int)nodecnt[n];
    float s0 = 0.f, s1 = 0.f, s2 = 0.f;
#pragma unroll 4
    for (int k = 0; k < cnt; ++k) {
        unsigned m = rec[((size_t)off + k) * 3];
        float2 zs = z2[m & 0x3FFFF];
        float e = fmaf(zs.x, a0, fmaf(zs.y, a1, cd));
        e = e >= 0.f ? e : 0.01f * e;
        float ex = __expf(e - 48.f);   // const shift cancels in softmax; e<=~88, den>=deg*e^-49
        s0 += ex; s1 += ex * zs.x; s2 += ex * zs.y;
    }
    acc2c[(size_t)0 * NN + n] = s0;
    acc2c[(size_t)1 * NN + n] = s1;
    acc2c[(size_t)2 * NN + n] = s2;
}

// x2 = num/den; f64 dot with mlp_w; block reduce; f64 atomic
__global__ void k_final(const float* __restrict__ acc2c, const float* __restrict__ mlp_w,
                        double* __restrict__ dacc) {
    int n = blockIdx.x * blockDim.x + threadIdx.x;
    double v = 0.0;
    if (n < NN) {
        float den = acc2c[(size_t)0 * NN + n];
        float n0  = acc2c[(size_t)1 * NN + n];
        float n1  = acc2c[(size_t)2 * NN + n];
        float x0 = den > 0.f ? n0 / den : 0.f;
        float x1 = den > 0.f ? n1 / den : 0.f;
        v = (double)x0 * (double)mlp_w[2 * n] + (double)x1 * (double)mlp_w[2 * n + 1];
    }
    for (int off = 32; off > 0; off >>= 1) v += __shfl_down(v, off);
    __shared__ double sm[4];
    int lane = threadIdx.x & 63, wid = threadIdx.x >> 6;
    if (lane == 0) sm[wid] = v;
    __syncthreads();
    if (threadIdx.x == 0) {
        double sum = sm[0] + sm[1] + sm[2] + sm[3];
        unsafeAtomicAdd(dacc, sum);
    }
}

__global__ void k_out(const double* __restrict__ dacc, const float* __restrict__ mlp_b,
                      float* __restrict__ out) {
    double logit = dacc[0] + (double)mlp_b[0];
    out[0] = (float)(1.0 / (1.0 + exp(-logit)));
}

extern "C" void kernel_launch(void* const* d_in, const int* in_sizes, int n_in,
                              void* d_out, int out_size, void* d_ws, size_t ws_size,
                              hipStream_t stream) {
    const float* h     = (const float*)d_in[0];
    const int*   src   = (const int*)d_in[1];
    const int*   dst   = (const int*)d_in[2];
    const float* fc1   = (const float*)d_in[3];
    const float* attn1 = (const float*)d_in[4];
    const float* fc2   = (const float*)d_in[5];
    const float* attn2 = (const float*)d_in[6];
    const float* mlp_w = (const float*)d_in[7];
    const float* mlp_b = (const float*)d_in[8];
    float* out = (float*)d_out;

    unsigned* ws      = (unsigned*)d_ws;
    double*   dacc    = (double*)d_ws;
    float*    uv      = (float*)(ws + W_UV);
    unsigned* cur     = ws + W_CUR;
    unsigned* nodeoff = ws + W_NOFF;
    unsigned* nodecnt = ws + W_NCNT;
    unsigned* rec     = ws + W_REC;
    float*    accc    = (float*)(ws + W_ACC);   // 6 planes layer1; first 3 reused layer2
    float2*   z2      = (float2*)(ws + W_Z2);

    const int NG = (NN + 255) / 256;            // 782

    hipLaunchKernelGGL(k_init, dim3(2), dim3(256), 0, stream, ws);
    hipLaunchKernelGGL(k_prep, dim3(1), dim3(64), 0, stream, fc1, attn1, uv);
    hipLaunchKernelGGL(k_scatter, dim3(NBLK_SC), dim3(SCT), 0, stream,
                       src, dst, (const float2*)h, rec, cur);
    hipLaunchKernelGGL(k_sort, dim3(NB), dim3(1024), 0, stream,
                       rec, cur, nodeoff, nodecnt);
    hipLaunchKernelGGL(k_gat1, dim3(NG), dim3(256), 0, stream,
                       rec, nodeoff, nodecnt, (const float2*)h, uv, accc);
    hipLaunchKernelGGL(k_node1, dim3(NG), dim3(256), 0, stream, accc, fc1, fc2, z2);
    hipLaunchKernelGGL(k_gat2, dim3(NG), dim3(256), 0, stream,
                       rec, nodeoff, nodecnt, (const float2*)z2, attn2, accc);
    hipLaunchKernelGGL(k_final, dim3(NG), dim3(256), 0, stream, accc, mlp_w, dacc);
    hipLaunchKernelGGL(k_out, dim3(1), dim3(1), 0, stream, dacc, mlp_b, out);
}

// Round 14
// 250.588 us; speedup vs baseline: 3.0450x; 1.3696x over previous
//
#include <hip/hip_runtime.h>
#include <hip/hip_bf16.h>
#include <math.h>

#define NN 200000
#define NE 6400000

#define BSHIFT 9
#define BNODES 512                     // nodes per bucket
#define NB 391                         // ceil(NN / 512)
#define CAP 17408                      // 17*1024; mean 16384, +8 sigma
#define NBLK_SC 256
#define SCT 1024                       // scatter block threads (16 waves)
#define CHUNK (NE / NBLK_SC)           // 25000; 25 iters/thread

// ---- workspace layout (4-byte words) ----
#define W_DACC 0                       // double (2 words)
#define W_UV   4                       // 8 floats
#define W_CUR  16                      // NB uints
#define W_NOFF 2048                    // NN uints: absolute record-slot offset per node
#define W_NCNT (W_NOFF + NN)           // NN uints: record count per node
#define W_META (W_NCNT + NN)           // NB*CAP u32 meta records: sn(18b) | dl(9b)<<18
#define W_ACC  (W_META + NB*CAP)       // 6*NN f32 planar [j*NN+n]; layer2 reuses 3 planes
#define W_Z2   (W_ACC + 6*NN)          // 2*NN f32 (float2/node)
#define W_TOTAL (W_Z2 + 2*NN)          // ~8.8M words = 35 MB

__global__ void k_init(unsigned* __restrict__ ws) {
    int t = blockIdx.x * blockDim.x + threadIdx.x;
    if (t == 0) *(double*)ws = 0.0;
    if (t < NB) ws[W_CUR + t] = 0u;
}

// u_i(h) = sum_o fc1[h][i][o]*attn1[h][o];  v_i(h) = sum_o fc1[h][i][o]*attn1[h][16+o]
__global__ void k_prep(const float* __restrict__ fc1, const float* __restrict__ attn1,
                       float* __restrict__ uv) {
    int t = threadIdx.x;
    if (t < 8) {
        int h = t >> 2, r = t & 3, i = r & 1, isv = r >> 1;
        double s = 0.0;
        for (int o = 0; o < 16; ++o)
            s += (double)fc1[h * 32 + i * 16 + o] * (double)attn1[h * 32 + isv * 16 + o];
        uv[t] = (float)s;
    }
}

// radix partition by dst bucket, 4B meta records, ONE LDS atomic per edge:
// the counting atomicAdd's return value IS the in-block rank; (d,rank) held in
// statically-indexed registers between the two phases.
__launch_bounds__(SCT)
__global__ void k_scatter(const int* __restrict__ src, const int* __restrict__ dst,
                          unsigned* __restrict__ meta, unsigned* __restrict__ cur) {
    __shared__ unsigned cnt[NB], gbase[NB];           // 3.1 KB
    for (int i = threadIdx.x; i < NB; i += SCT) cnt[i] = 0u;
    __syncthreads();
    int beg = blockIdx.x * CHUNK;
    unsigned pack[25];                                // d(18b) | rank(14b)<<18
#pragma unroll
    for (int k = 0; k < 25; ++k) {
        int j = k * SCT + threadIdx.x;
        pack[k] = 0xFFFFFFFFu;                        // d-field 0x3FFFF impossible (d<200000)
        if (j < CHUNK) {
            unsigned d = (unsigned)__builtin_nontemporal_load(dst + beg + j);
            unsigned rank = atomicAdd(&cnt[d >> BSHIFT], 1u);   // count == rank assignment
            pack[k] = d | (rank << 18);               // per-block bucket count ~64 << 2^14
        }
    }
    __syncthreads();
    for (int i = threadIdx.x; i < NB; i += SCT)
        gbase[i] = cnt[i] ? atomicAdd(&cur[i], cnt[i]) : 0u;
    __syncthreads();
#pragma unroll
    for (int k = 0; k < 25; ++k) {
        if (pack[k] != 0xFFFFFFFFu) {
            int j = k * SCT + threadIdx.x;
            unsigned d = pack[k] & 0x3FFFFu;
            unsigned b = d >> BSHIFT;
            unsigned slot = gbase[b] + (pack[k] >> 18);
            if (slot < CAP) {
                unsigned sn = (unsigned)__builtin_nontemporal_load(src + beg + j);
                meta[(size_t)b * CAP + slot] = sn | ((d & (BNODES - 1)) << 18);
            }
        }
    }
}

// in-place counting sort by node within each bucket; records staged in registers
// (17/thread, static); ONE LDS atomic per edge (histogram return value = rank).
__launch_bounds__(1024)
__global__ void k_sort(unsigned* __restrict__ meta, const unsigned* __restrict__ cur,
                       unsigned* __restrict__ nodeoff, unsigned* __restrict__ nodecnt) {
    __shared__ unsigned hist[BNODES], base[BNODES], scan[BNODES];   // 6 KB
    int b = blockIdx.x, t = threadIdx.x;
    size_t boff = (size_t)b * CAP;
    int cnt = min((int)cur[b], CAP);
    for (int i = t; i < BNODES; i += 1024) hist[i] = 0u;
    __syncthreads();
    unsigned rm[17], rr[17];
#pragma unroll
    for (int k = 0; k < 17; ++k) {
        int i = k * 1024 + t;
        rm[k] = 0xFFFFFFFFu;
        rr[k] = 0u;
        if (i < cnt) {
            rm[k] = meta[boff + i];
            rr[k] = atomicAdd(&hist[rm[k] >> 18], 1u);    // rank within node
        }
    }
    asm volatile("s_waitcnt vmcnt(0)" ::: "memory");      // all reads done before writes
    __syncthreads();
    if (t < BNODES) scan[t] = hist[t];
    __syncthreads();
    for (int d = 1; d < BNODES; d <<= 1) {                // Hillis-Steele inclusive scan
        unsigned v = 0u;
        if (t < BNODES && t >= d) v = scan[t - d];
        __syncthreads();
        if (t < BNODES) scan[t] += v;
        __syncthreads();
    }
    int nb = b * BNODES;
    int nn = min(BNODES, NN - nb);
    if (t < BNODES) {
        unsigned ex = scan[t] - hist[t];                  // exclusive base
        base[t] = ex;
        if (t < nn) {
            nodeoff[nb + t] = (unsigned)boff + ex;
            nodecnt[nb + t] = hist[t];
        }
    }
    __syncthreads();
#pragma unroll
    for (int k = 0; k < 17; ++k)
        if (rm[k] != 0xFFFFFFFFu)
            meta[boff + base[rm[k] >> 18] + rr[k]] = rm[k];
}

// layer-1: thread-per-node, ZERO atomics; h[sn] gathers hit the L2-resident 1.6 MB h.
__global__ void k_gat1(const unsigned* __restrict__ meta, const unsigned* __restrict__ nodeoff,
                       const unsigned* __restrict__ nodecnt, const float2* __restrict__ h,
                       const float* __restrict__ uv, float* __restrict__ accc) {
    int n = blockIdx.x * blockDim.x + threadIdx.x;
    if (n >= NN) return;
    float u00 = uv[0], u10 = uv[1], v00 = uv[2], v10 = uv[3];
    float u01 = uv[4], u11 = uv[5], v01 = uv[6], v11 = uv[7];
    float2 hd = h[n];
    float c0 = fmaf(hd.x, v00, hd.y * v10);
    float c1 = fmaf(hd.x, v01, hd.y * v11);
    unsigned off = nodeoff[n];
    int cnt = (int)nodecnt[n];
    float s0 = 0.f, s1 = 0.f, s2 = 0.f, s3 = 0.f, s4 = 0.f, s5 = 0.f;
#pragma unroll 4
    for (int k = 0; k < cnt; ++k) {
        unsigned m = meta[(size_t)off + k];
        float2 hs = h[m & 0x3FFFF];
        float e0 = fmaf(hs.x, u00, fmaf(hs.y, u10, c0));
        float e1 = fmaf(hs.x, u01, fmaf(hs.y, u11, c1));
        e0 = e0 >= 0.f ? e0 : 0.01f * e0;
        e1 = e1 >= 0.f ? e1 : 0.01f * e1;
        float ex0 = __expf(e0);
        float ex1 = __expf(e1);
        s0 += ex0; s1 += ex0 * hs.x; s2 += ex0 * hs.y;
        s3 += ex1; s4 += ex1 * hs.x; s5 += ex1 * hs.y;
    }
    accc[(size_t)0 * NN + n] = s0;
    accc[(size_t)1 * NN + n] = s1;
    accc[(size_t)2 * NN + n] = s2;
    accc[(size_t)3 * NN + n] = s3;
    accc[(size_t)4 * NN + n] = s4;
    accc[(size_t)5 * NN + n] = s5;
}

// finalize layer1 (softmax div + elu), z2 = x @ fc2
__global__ void k_node1(const float* __restrict__ accc, const float* __restrict__ fc1,
                        const float* __restrict__ fc2, float2* __restrict__ z2) {
    int n = blockIdx.x * blockDim.x + threadIdx.x;
    if (n >= NN) return;
    float a[6];
#pragma unroll
    for (int j = 0; j < 6; ++j) a[j] = accc[(size_t)j * NN + n];
    float den0 = a[0], A0 = a[1], B0 = a[2];
    float den1 = a[3], A1 = a[4], B1 = a[5];
    float x[32];
#pragma unroll
    for (int o = 0; o < 16; ++o) {
        float t0 = den0 > 0.f ? (A0 * fc1[o]      + B0 * fc1[16 + o]) / den0 : 0.f;
        float t1 = den1 > 0.f ? (A1 * fc1[32 + o] + B1 * fc1[48 + o]) / den1 : 0.f;
        x[o]      = t0 > 0.f ? t0 : expm1f(t0);
        x[16 + o] = t1 > 0.f ? t1 : expm1f(t1);
    }
    float z0 = 0.f, z1 = 0.f;
#pragma unroll
    for (int j = 0; j < 32; ++j) {
        z0 += x[j] * fc2[2 * j];
        z1 += x[j] * fc2[2 * j + 1];
    }
    z2[n] = make_float2(z0, z1);
}

// layer-2: thread-per-node, ZERO atomics; z2[sn] gathers are L2-resident (1.6 MB).
__global__ void k_gat2(const unsigned* __restrict__ meta, const unsigned* __restrict__ nodeoff,
                       const unsigned* __restrict__ nodecnt, const float2* __restrict__ z2,
                       const float* __restrict__ attn2, float* __restrict__ acc2c) {
    int n = blockIdx.x * blockDim.x + threadIdx.x;
    if (n >= NN) return;
    float a0 = attn2[0], a1 = attn2[1], a2 = attn2[2], a3 = attn2[3];
    float2 zd = z2[n];
    float cd = fmaf(zd.x, a2, zd.y * a3);
    unsigned off = nodeoff[n];
    int cnt = (int)nodecnt[n];
    float s0 = 0.f, s1 = 0.f, s2 = 0.f;
#pragma unroll 4
    for (int k = 0; k < cnt; ++k) {
        unsigned m = meta[(size_t)off + k];
        float2 zs = z2[m & 0x3FFFF];
        float e = fmaf(zs.x, a0, fmaf(zs.y, a1, cd));
        e = e >= 0.f ? e : 0.01f * e;
        float ex = __expf(e - 48.f);   // const shift cancels in softmax; e<=~88, den>=deg*e^-49
        s0 += ex; s1 += ex * zs.x; s2 += ex * zs.y;
    }
    acc2c[(size_t)0 * NN + n] = s0;
    acc2c[(size_t)1 * NN + n] = s1;
    acc2c[(size_t)2 * NN + n] = s2;
}

// x2 = num/den; f64 dot with mlp_w; block reduce; f64 atomic
__global__ void k_final(const float* __restrict__ acc2c, const float* __restrict__ mlp_w,
                        double* __restrict__ dacc) {
    int n = blockIdx.x * blockDim.x + threadIdx.x;
    double v = 0.0;
    if (n < NN) {
        float den = acc2c[(size_t)0 * NN + n];
        float n0  = acc2c[(size_t)1 * NN + n];
        float n1  = acc2c[(size_t)2 * NN + n];
        float x0 = den > 0.f ? n0 / den : 0.f;
        float x1 = den > 0.f ? n1 / den : 0.f;
        v = (double)x0 * (double)mlp_w[2 * n] + (double)x1 * (double)mlp_w[2 * n + 1];
    }
    for (int off = 32; off > 0; off >>= 1) v += __shfl_down(v, off);
    __shared__ double sm[4];
    int lane = threadIdx.x & 63, wid = threadIdx.x >> 6;
    if (lane == 0) sm[wid] = v;
    __syncthreads();
    if (threadIdx.x == 0) {
        double sum = sm[0] + sm[1] + sm[2] + sm[3];
        unsafeAtomicAdd(dacc, sum);
    }
}

__global__ void k_out(const double* __restrict__ dacc, const float* __restrict__ mlp_b,
                      float* __restrict__ out) {
    double logit = dacc[0] + (double)mlp_b[0];
    out[0] = (float)(1.0 / (1.0 + exp(-logit)));
}

extern "C" void kernel_launch(void* const* d_in, const int* in_sizes, int n_in,
                              void* d_out, int out_size, void* d_ws, size_t ws_size,
                              hipStream_t stream) {
    const float* h     = (const float*)d_in[0];
    const int*   src   = (const int*)d_in[1];
    const int*   dst   = (const int*)d_in[2];
    const float* fc1   = (const float*)d_in[3];
    const float* attn1 = (const float*)d_in[4];
    const float* fc2   = (const float*)d_in[5];
    const float* attn2 = (const float*)d_in[6];
    const float* mlp_w = (const float*)d_in[7];
    const float* mlp_b = (const float*)d_in[8];
    float* out = (float*)d_out;

    unsigned* ws      = (unsigned*)d_ws;
    double*   dacc    = (double*)d_ws;
    float*    uv      = (float*)(ws + W_UV);
    unsigned* cur     = ws + W_CUR;
    unsigned* nodeoff = ws + W_NOFF;
    unsigned* nodecnt = ws + W_NCNT;
    unsigned* meta    = ws + W_META;
    float*    accc    = (float*)(ws + W_ACC);   // 6 planes layer1; first 3 reused layer2
    float2*   z2      = (float2*)(ws + W_Z2);

    const int NG = (NN + 255) / 256;            // 782

    hipLaunchKernelGGL(k_init, dim3(2), dim3(256), 0, stream, ws);
    hipLaunchKernelGGL(k_prep, dim3(1), dim3(64), 0, stream, fc1, attn1, uv);
    hipLaunchKernelGGL(k_scatter, dim3(NBLK_SC), dim3(SCT), 0, stream,
                       src, dst, meta, cur);
    hipLaunchKernelGGL(k_sort, dim3(NB), dim3(1024), 0, stream,
                       meta, cur, nodeoff, nodecnt);
    hipLaunchKernelGGL(k_gat1, dim3(NG), dim3(256), 0, stream,
                       meta, nodeoff, nodecnt, (const float2*)h, uv, accc);
    hipLaunchKernelGGL(k_node1, dim3(NG), dim3(256), 0, stream, accc, fc1, fc2, z2);
    hipLaunchKernelGGL(k_gat2, dim3(NG), dim3(256), 0, stream,
                       meta, nodeoff, nodecnt, (const float2*)z2, attn2, accc);
    hipLaunchKernelGGL(k_final, dim3(NG), dim3(256), 0, stream, accc, mlp_w, dacc);
    hipLaunchKernelGGL(k_out, dim3(1), dim3(1), 0, stream, dacc, mlp_b, out);
}

// Round 15
// 240.709 us; speedup vs baseline: 3.1699x; 1.0410x over previous
//
#include <hip/hip_runtime.h>
#include <hip/hip_bf16.h>
#include <math.h>

#define NN 200000
#define NE 6400000

#define BNODES 782                     // nodes per bucket (non-pow2: NB = 256 = #CUs)
#define NB 256
#define CAP 27648                      // 27*1024; mean 25000, sigma ~158 -> +16 sigma
#define NBLK_SC 256
#define SCT 1024                       // scatter/sort block threads (16 waves)
#define CHUNK (NE / NBLK_SC)           // 25000; 25 iters/thread
#define SREG 27                        // sort: ceil(CAP/1024) register records/thread

// ---- workspace layout (4-byte words) ----
#define W_DACC 0                       // double (2 words)
#define W_UV   4                       // 8 floats
#define W_CUR  16                      // NB uints
#define W_NOFF 1024                    // NN uints: absolute record-slot offset per node
#define W_NCNT (W_NOFF + NN)           // NN uints: record count per node
#define W_META (W_NCNT + NN)           // NB*CAP u32 meta: sn(18b) | dl(10b)<<18
#define W_Z2   (W_META + NB*CAP)       // 2*NN f32 (float2/node)
#define W_TOTAL (W_Z2 + 2*NN)          // ~7.9M words = 31.5 MB

__global__ void k_init(unsigned* __restrict__ ws) {
    int t = blockIdx.x * blockDim.x + threadIdx.x;
    if (t == 0) *(double*)ws = 0.0;
    if (t < NB) ws[W_CUR + t] = 0u;
}

// u_i(h) = sum_o fc1[h][i][o]*attn1[h][o];  v_i(h) = sum_o fc1[h][i][o]*attn1[h][16+o]
__global__ void k_prep(const float* __restrict__ fc1, const float* __restrict__ attn1,
                       float* __restrict__ uv) {
    int t = threadIdx.x;
    if (t < 8) {
        int h = t >> 2, r = t & 3, i = r & 1, isv = r >> 1;
        double s = 0.0;
        for (int o = 0; o < 16; ++o)
            s += (double)fc1[h * 32 + i * 16 + o] * (double)attn1[h * 32 + isv * 16 + o];
        uv[t] = (float)s;
    }
}

// radix partition by dst bucket (b = d/782), 4B meta records, ONE LDS atomic/edge.
__launch_bounds__(SCT)
__global__ void k_scatter(const int* __restrict__ src, const int* __restrict__ dst,
                          unsigned* __restrict__ meta, unsigned* __restrict__ cur) {
    __shared__ unsigned cnt[NB], gbase[NB];           // 2 KB
    for (int i = threadIdx.x; i < NB; i += SCT) cnt[i] = 0u;
    __syncthreads();
    int beg = blockIdx.x * CHUNK;
    unsigned pack[25];                                // d(18b) | rank(14b)<<18
#pragma unroll
    for (int k = 0; k < 25; ++k) {
        int j = k * SCT + threadIdx.x;
        pack[k] = 0xFFFFFFFFu;                        // d-field 0x3FFFF impossible (d<200000)
        if (j < CHUNK) {
            unsigned d = (unsigned)__builtin_nontemporal_load(dst + beg + j);
            unsigned rank = atomicAdd(&cnt[d / BNODES], 1u);   // count == rank
            pack[k] = d | (rank << 18);               // rank ~<300 << 2^14
        }
    }
    __syncthreads();
    for (int i = threadIdx.x; i < NB; i += SCT)
        gbase[i] = cnt[i] ? atomicAdd(&cur[i], cnt[i]) : 0u;
    __syncthreads();
#pragma unroll
    for (int k = 0; k < 25; ++k) {
        if (pack[k] != 0xFFFFFFFFu) {
            int j = k * SCT + threadIdx.x;
            unsigned d = pack[k] & 0x3FFFFu;
            unsigned b = d / BNODES;
            unsigned dl = d - b * BNODES;
            unsigned slot = gbase[b] + (pack[k] >> 18);
            if (slot < CAP) {
                unsigned sn = (unsigned)__builtin_nontemporal_load(src + beg + j);
                meta[(size_t)b * CAP + slot] = sn | (dl << 18);
            }
        }
    }
}

// in-place counting sort by node within each bucket; 256 blocks (1/CU, balanced);
// records staged in registers (27/thread, static); ONE LDS atomic/edge.
__launch_bounds__(SCT)
__global__ void k_sort(unsigned* __restrict__ meta, const unsigned* __restrict__ cur,
                       unsigned* __restrict__ nodeoff, unsigned* __restrict__ nodecnt) {
    __shared__ unsigned hist[BNODES], base[BNODES], scan[BNODES];   // 9.4 KB
    int b = blockIdx.x, t = threadIdx.x;
    size_t boff = (size_t)b * CAP;
    int cnt = min((int)cur[b], CAP);
    for (int i = t; i < BNODES; i += SCT) hist[i] = 0u;
    __syncthreads();
    unsigned rm[SREG], rr[SREG];
#pragma unroll
    for (int k = 0; k < SREG; ++k) {
        int i = k * SCT + t;
        rm[k] = 0xFFFFFFFFu;
        rr[k] = 0u;
        if (i < cnt) {
            rm[k] = meta[boff + i];
            rr[k] = atomicAdd(&hist[rm[k] >> 18], 1u);    // rank within node
        }
    }
    asm volatile("s_waitcnt vmcnt(0)" ::: "memory");      // all reads before any write
    __syncthreads();
    if (t < BNODES) scan[t] = hist[t];
    __syncthreads();
    for (int d = 1; d < BNODES; d <<= 1) {                // Hillis-Steele inclusive scan
        unsigned v = 0u;
        if (t < BNODES && t >= d) v = scan[t - d];
        __syncthreads();
        if (t < BNODES) scan[t] += v;
        __syncthreads();
    }
    int nb = b * BNODES;
    int nn = min(BNODES, NN - nb);
    if (t < BNODES) {
        unsigned ex = scan[t] - hist[t];                  // exclusive base
        base[t] = ex;
        if (t < nn) {
            nodeoff[nb + t] = (unsigned)boff + ex;
            nodecnt[nb + t] = hist[t];
        }
    }
    __syncthreads();
#pragma unroll
    for (int k = 0; k < SREG; ++k)
        if (rm[k] != 0xFFFFFFFFu)
            meta[boff + base[rm[k] >> 18] + rr[k]] = rm[k];
}

// layer-1 + node finalize fused: thread-per-node, zero atomics; h gathers L2-hit;
// acc stays in registers; writes only z2.
__global__ void k_gat1(const unsigned* __restrict__ meta, const unsigned* __restrict__ nodeoff,
                       const unsigned* __restrict__ nodecnt, const float2* __restrict__ h,
                       const float* __restrict__ uv, const float* __restrict__ fc1,
                       const float* __restrict__ fc2, float2* __restrict__ z2) {
    int n = blockIdx.x * blockDim.x + threadIdx.x;
    if (n >= NN) return;
    float u00 = uv[0], u10 = uv[1], v00 = uv[2], v10 = uv[3];
    float u01 = uv[4], u11 = uv[5], v01 = uv[6], v11 = uv[7];
    float2 hd = h[n];
    float c0 = fmaf(hd.x, v00, hd.y * v10);
    float c1 = fmaf(hd.x, v01, hd.y * v11);
    unsigned off = nodeoff[n];
    int cnt = (int)nodecnt[n];
    float s0 = 0.f, s1 = 0.f, s2 = 0.f, s3 = 0.f, s4 = 0.f, s5 = 0.f;
#pragma unroll 4
    for (int k = 0; k < cnt; ++k) {
        unsigned m = meta[(size_t)off + k];
        float2 hs = h[m & 0x3FFFF];
        float e0 = fmaf(hs.x, u00, fmaf(hs.y, u10, c0));
        float e1 = fmaf(hs.x, u01, fmaf(hs.y, u11, c1));
        e0 = e0 >= 0.f ? e0 : 0.01f * e0;
        e1 = e1 >= 0.f ? e1 : 0.01f * e1;
        float ex0 = __expf(e0);
        float ex1 = __expf(e1);
        s0 += ex0; s1 += ex0 * hs.x; s2 += ex0 * hs.y;
        s3 += ex1; s4 += ex1 * hs.x; s5 += ex1 * hs.y;
    }
    // node1 math inline: softmax div + elu + z2 = x @ fc2
    float z0 = 0.f, z1 = 0.f;
#pragma unroll
    for (int o = 0; o < 16; ++o) {
        float t0 = s0 > 0.f ? (s1 * fc1[o]      + s2 * fc1[16 + o]) / s0 : 0.f;
        float t1 = s3 > 0.f ? (s4 * fc1[32 + o] + s5 * fc1[48 + o]) / s3 : 0.f;
        float x0 = t0 > 0.f ? t0 : expm1f(t0);
        float x1 = t1 > 0.f ? t1 : expm1f(t1);
        z0 += x0 * fc2[2 * o]      + x1 * fc2[2 * (16 + o)];
        z1 += x0 * fc2[2 * o + 1]  + x1 * fc2[2 * (16 + o) + 1];
    }
    z2[n] = make_float2(z0, z1);
}

// layer-2 + final MLP dot fused: thread-per-node, zero atomics; f64 block reduce.
__global__ void k_gat2(const unsigned* __restrict__ meta, const unsigned* __restrict__ nodeoff,
                       const unsigned* __restrict__ nodecnt, const float2* __restrict__ z2,
                       const float* __restrict__ attn2, const float* __restrict__ mlp_w,
                       double* __restrict__ dacc) {
    int n = blockIdx.x * blockDim.x + threadIdx.x;
    double v = 0.0;
    if (n < NN) {
        float a0 = attn2[0], a1 = attn2[1], a2 = attn2[2], a3 = attn2[3];
        float2 zd = z2[n];
        float cd = fmaf(zd.x, a2, zd.y * a3);
        unsigned off = nodeoff[n];
        int cnt = (int)nodecnt[n];
        float s0 = 0.f, s1 = 0.f, s2 = 0.f;
#pragma unroll 4
        for (int k = 0; k < cnt; ++k) {
            unsigned m = meta[(size_t)off + k];
            float2 zs = z2[m & 0x3FFFF];
            float e = fmaf(zs.x, a0, fmaf(zs.y, a1, cd));
            e = e >= 0.f ? e : 0.01f * e;
            float ex = __expf(e - 48.f);   // const shift cancels; e<=~88, den>=deg*e^-49
            s0 += ex; s1 += ex * zs.x; s2 += ex * zs.y;
        }
        float x0 = s0 > 0.f ? s1 / s0 : 0.f;
        float x1 = s0 > 0.f ? s2 / s0 : 0.f;
        v = (double)x0 * (double)mlp_w[2 * n] + (double)x1 * (double)mlp_w[2 * n + 1];
    }
    for (int off = 32; off > 0; off >>= 1) v += __shfl_down(v, off);
    __shared__ double sm[4];
    int lane = threadIdx.x & 63, wid = threadIdx.x >> 6;
    if (lane == 0) sm[wid] = v;
    __syncthreads();
    if (threadIdx.x == 0) {
        double sum = sm[0] + sm[1] + sm[2] + sm[3];
        unsafeAtomicAdd(dacc, sum);   // 782 device f64 atomics: negligible
    }
}

__global__ void k_out(const double* __restrict__ dacc, const float* __restrict__ mlp_b,
                      float* __restrict__ out) {
    double logit = dacc[0] + (double)mlp_b[0];
    out[0] = (float)(1.0 / (1.0 + exp(-logit)));
}

extern "C" void kernel_launch(void* const* d_in, const int* in_sizes, int n_in,
                              void* d_out, int out_size, void* d_ws, size_t ws_size,
                              hipStream_t stream) {
    const float* h     = (const float*)d_in[0];
    const int*   src   = (const int*)d_in[1];
    const int*   dst   = (const int*)d_in[2];
    const float* fc1   = (const float*)d_in[3];
    const float* attn1 = (const float*)d_in[4];
    const float* fc2   = (const float*)d_in[5];
    const float* attn2 = (const float*)d_in[6];
    const float* mlp_w = (const float*)d_in[7];
    const float* mlp_b = (const float*)d_in[8];
    float* out = (float*)d_out;

    unsigned* ws      = (unsigned*)d_ws;
    double*   dacc    = (double*)d_ws;
    float*    uv      = (float*)(ws + W_UV);
    unsigned* cur     = ws + W_CUR;
    unsigned* nodeoff = ws + W_NOFF;
    unsigned* nodecnt = ws + W_NCNT;
    unsigned* meta    = ws + W_META;
    float2*   z2      = (float2*)(ws + W_Z2);

    const int NG = (NN + 255) / 256;            // 782

    hipLaunchKernelGGL(k_init, dim3(1), dim3(256), 0, stream, ws);
    hipLaunchKernelGGL(k_prep, dim3(1), dim3(64), 0, stream, fc1, attn1, uv);
    hipLaunchKernelGGL(k_scatter, dim3(NBLK_SC), dim3(SCT), 0, stream,
                       src, dst, meta, cur);
    hipLaunchKernelGGL(k_sort, dim3(NB), dim3(SCT), 0, stream,
                       meta, cur, nodeoff, nodecnt);
    hipLaunchKernelGGL(k_gat1, dim3(NG), dim3(256), 0, stream,
                       meta, nodeoff, nodecnt, (const float2*)h, uv, fc1, fc2, z2);
    hipLaunchKernelGGL(k_gat2, dim3(NG), dim3(256), 0, stream,
                       meta, nodeoff, nodecnt, (const float2*)z2, attn2, mlp_w, dacc);
    hipLaunchKernelGGL(k_out, dim3(1), dim3(1), 0, stream, dacc, mlp_b, out);
}